// Round 1
// baseline (14035.950 us; speedup 1.0000x reference)
//
#include <hip/hip_runtime.h>
#include <hip/hip_bf16.h>

#define TT 512
#define BB 256
#define SS 256
#define AA 8
#define DD 64

typedef unsigned short ushort_t;
typedef __bf16 bf16x8 __attribute__((ext_vector_type(8)));
typedef float  f32x4  __attribute__((ext_vector_type(4)));

__device__ __forceinline__ ushort_t f2bf(float x) {
  union { float f; unsigned u; } v; v.f = x;
  unsigned r = (v.u + 0x7FFFu + ((v.u >> 16) & 1u)) >> 16;
  return (ushort_t)r;
}

// ---------------- prologue: per-state Gaussian params ----------------
__global__ __launch_bounds__(64) void k_params(const float* __restrict__ mu,
                                               const float* __restrict__ lv,
                                               float* __restrict__ A1, float* __restrict__ A2,
                                               float* __restrict__ Cs) {
  const float LOG2PI = 1.8378770664093453f;
  int s = blockIdx.x, d = threadIdx.x;
  float l = lv[s * DD + d], m_ = mu[s * DD + d];
  float inv = __expf(-l);
  A1[s * DD + d] = inv;
  A2[s * DD + d] = m_ * inv;
  float part = m_ * m_ * inv + l;
  #pragma unroll
  for (int o = 32; o >= 1; o >>= 1) part += __shfl_down(part, o);
  if (d == 0) Cs[s] = part + (float)DD * LOG2PI;
}

// ---------------- prologue: log_softmax of s0_logits ----------------
__global__ __launch_bounds__(256) void k_pi0(const float* __restrict__ s0, float* __restrict__ lp0) {
  __shared__ float red[4];
  int tid = threadIdx.x, ln = tid & 63, wv = tid >> 6;
  float v = s0[tid];
  float m = v;
  #pragma unroll
  for (int o = 32; o >= 1; o >>= 1) m = fmaxf(m, __shfl_xor(m, o));
  if (ln == 0) red[wv] = m;
  __syncthreads();
  m = fmaxf(fmaxf(red[0], red[1]), fmaxf(red[2], red[3]));
  __syncthreads();
  float e = __expf(v - m);
  float s = e;
  #pragma unroll
  for (int o = 32; o >= 1; o >>= 1) s += __shfl_xor(s, o);
  if (ln == 0) red[wv] = s;
  __syncthreads();
  s = red[0] + red[1] + red[2] + red[3];
  lp0[tid] = v - m - __logf(s);
}

// ---------------- prologue: softmax(w_logits) -> bf16 MFMA B-fragment layouts ----------------
// Wf[fragid][lane][e]: fragid=(a*8+kc)*16+ntile ; fwd: K=(a,i), N=j
// Wb: same, bwd: K=(a,j), N=i
__global__ __launch_bounds__(256) void k_trans(const float* __restrict__ wl,
                                               ushort_t* __restrict__ Wf, ushort_t* __restrict__ Wb) {
  int tid = threadIdx.x;
  int rl = tid >> 5, l = tid & 31;
  int row = blockIdx.x * 8 + rl;      // row = a*256 + i
  int a = row >> 8, i = row & 255;
  const float* src = wl + (size_t)row * 256 + l * 8;
  float v[8];
  *reinterpret_cast<float4*>(&v[0]) = *reinterpret_cast<const float4*>(src);
  *reinterpret_cast<float4*>(&v[4]) = *reinterpret_cast<const float4*>(src + 4);
  float m = v[0];
  #pragma unroll
  for (int k = 1; k < 8; ++k) m = fmaxf(m, v[k]);
  #pragma unroll
  for (int o = 16; o >= 1; o >>= 1) m = fmaxf(m, __shfl_xor(m, o, 32));
  float s = 0.f;
  #pragma unroll
  for (int k = 0; k < 8; ++k) { v[k] = __expf(v[k] - m); s += v[k]; }
  #pragma unroll
  for (int o = 16; o >= 1; o >>= 1) s += __shfl_xor(s, o, 32);
  float inv = 1.0f / s;
  #pragma unroll
  for (int k = 0; k < 8; ++k) {
    int j = l * 8 + k;
    ushort_t h = f2bf(v[k] * inv);
    size_t fi = (size_t)((a * 8 + (i >> 5)) * 16 + (j >> 4));
    Wf[fi * 512 + (((i >> 3) & 3) * 16 + (j & 15)) * 8 + (i & 7)] = h;
    size_t bi = (size_t)((a * 8 + (j >> 5)) * 16 + (i >> 4));
    Wb[bi * 512 + (((j >> 3) & 3) * 16 + (i & 15)) * 8 + (j & 7)] = h;
  }
}

// ---------------- logp_x [T,B,S] in fp32 + per-row max ----------------
__global__ __launch_bounds__(256) void k_logp(const float* __restrict__ x,
    const float* __restrict__ A1, const float* __restrict__ A2,
    const float* __restrict__ Cs, float* __restrict__ logp, float* __restrict__ Mmax) {
  __shared__ float sA1[64][64];
  __shared__ float sA2[64][64];
  int tid = threadIdx.x;
  int row = tid >> 3, dg = tid & 7;          // 32 rows/block, 8 threads per row
  size_t row0 = (size_t)blockIdx.x * 32;
  const float* xp = x + (row0 + row) * DD + dg * 8;
  float xv[8];
  *reinterpret_cast<float4*>(&xv[0]) = *reinterpret_cast<const float4*>(xp);
  *reinterpret_cast<float4*>(&xv[4]) = *reinterpret_cast<const float4*>(xp + 4);
  float m = -3.0e38f;
  float* orow = logp + (row0 + row) * SS;
  for (int st = 0; st < 4; ++st) {
    __syncthreads();
    #pragma unroll
    for (int k = 0; k < 4; ++k) {
      int flat = k * 1024 + tid * 4;
      int sr = flat >> 6, sc = flat & 63;
      *reinterpret_cast<float4*>(&sA1[sr][sc]) = *reinterpret_cast<const float4*>(&A1[(size_t)(st * 64 + sr) * 64 + sc]);
      *reinterpret_cast<float4*>(&sA2[sr][sc]) = *reinterpret_cast<const float4*>(&A2[(size_t)(st * 64 + sr) * 64 + sc]);
    }
    __syncthreads();
    for (int s = 0; s < 64; ++s) {
      float acc = 0.f;
      #pragma unroll
      for (int j = 0; j < 8; ++j) {
        float t1 = __builtin_fmaf(sA1[s][dg * 8 + j], xv[j], -2.0f * sA2[s][dg * 8 + j]);
        acc = __builtin_fmaf(t1, xv[j], acc);
      }
      acc += __shfl_xor(acc, 1, 8);
      acc += __shfl_xor(acc, 2, 8);
      acc += __shfl_xor(acc, 4, 8);
      float lp = -0.5f * (acc + Cs[st * 64 + s]);
      m = fmaxf(m, lp);
      if (((s ^ dg) & 7) == 0) orow[st * 64 + s] = lp;
    }
  }
  if (dg == 0) Mmax[row0 + row] = m;
}

// ---------------- recursion: fwd (blocks->groups 0..15) + bwd (16..31) concurrently ----------------
__global__ __launch_bounds__(256, 2) void k_recur(
    const float* __restrict__ a_in, const float* __restrict__ mask,
    float* __restrict__ out, float* __restrict__ beta,
    const float* __restrict__ logp, const float* __restrict__ Mmax,
    float* __restrict__ cvec, float* __restrict__ rvec,
    const ushort_t* __restrict__ Wf, const ushort_t* __restrict__ Wb,
    const float* __restrict__ lp0, int* __restrict__ bars) {
  const float EPSF  = 1e-6f;
  const float EPS_S = 256.0f * 1e-6f;
  const int tid  = threadIdx.x;
  const int lane = tid & 63;
  const int wave = tid >> 6;
  // XCD-local group swizzle (heuristic: xcd = blockIdx % 8)
  const int xcd  = blockIdx.x & 7;
  const int slot = blockIdx.x >> 3;
  const int wg   = slot & 7;                 // 8 WGs per group
  const int grpg = (slot >> 3) * 8 + xcd;    // 0..31
  const bool isF = (grpg < 16);
  const int grp  = grpg & 15;
  const int b0   = grp * 16;                 // 16 batches per group
  const int jc0  = wg * 32;                  // 32 output cols per WG
  int* bar = bars + grpg;

  __shared__ ushort_t stage[16][264];        // bf16 staged A-operand (padded)
  __shared__ float  w8s[16][8];
  __shared__ float  yred[4][2][64][4];
  __shared__ float  lxs[16][32];
  __shared__ float  rowA[16];
  __shared__ float  rowM[16];
  __shared__ float  rowG[16];
  __shared__ float  rowMk[16];

  // persistent W fragments: per wave K-quarter (kc = wave*2 + kk), 2 n-tiles
  bf16x8 bfrag[8][2][2];
  {
    const ushort_t* Ws = isF ? Wf : Wb;
    #pragma unroll
    for (int a = 0; a < 8; ++a)
      #pragma unroll
      for (int kk = 0; kk < 2; ++kk)
        #pragma unroll
        for (int nt = 0; nt < 2; ++nt) {
          const int kc = wave * 2 + kk;
          const int fragid = (a * 8 + kc) * 16 + wg * 2 + nt;
          bfrag[a][kk][nt] = *reinterpret_cast<const bf16x8*>(Ws + (size_t)fragid * 512 + lane * 8);
        }
  }

  const int m_ = lane & 15;
  const int q_ = lane >> 4;
  const int frow = tid >> 4;                 // finalize (row, col)
  const int fcol = tid & 15;
  const int lsrc = (frow >> 2) * 16 + fcol;  // lane holding C[frow][fcol]
  const int rg_  = frow & 3;

  if (isF) {
    // ---- t = 0 init: b1_hat = exp(lx0 - M + logpi0)
    {
      float mm = Mmax[b0 + frow];
      float csum = 0.f;
      #pragma unroll
      for (int nt = 0; nt < 2; ++nt) {
        int j = jc0 + nt * 16 + fcol;
        float lx = logp[(size_t)(b0 + frow) * SS + j];
        float v = __expf(lx - mm + lp0[j]);
        out[(size_t)(b0 + frow) * SS + j] = v;
        csum += v;
      }
      #pragma unroll
      for (int o = 8; o >= 1; o >>= 1) csum += __shfl_down(csum, o, 16);
      if (fcol == 0) atomicAdd(&cvec[b0 + frow], csum);
    }
    __threadfence();
    __syncthreads();
    if (tid == 0) {
      atomicAdd(bar, 1);
      while (__hip_atomic_load(bar, __ATOMIC_ACQUIRE, __HIP_MEMORY_SCOPE_AGENT) < 8)
        __builtin_amdgcn_s_sleep(1);
    }
    __syncthreads();

    for (int t = 1; t < TT; ++t) {
      // phase a: per-row scalars + lx tile
      if (tid < 16) {
        rowA[tid] = 1.0f / cvec[(size_t)(t - 1) * BB + b0 + tid];
        rowM[tid] = Mmax[(size_t)t * BB + b0 + tid];
      }
      if (tid < 128) {
        int r = tid >> 3, a2 = tid & 7;
        w8s[r][a2] = a_in[((size_t)(t - 1) * BB + b0 + r) * AA + a2];
      }
      {
        const float* lsp = logp + ((size_t)t * BB + b0 + frow) * SS + jc0;
        float2 v = *reinterpret_cast<const float2*>(lsp + fcol * 2);
        lxs[frow][fcol * 2] = v.x;
        lxs[frow][fcol * 2 + 1] = v.y;
      }
      __syncthreads();
      // phase b: stage alpha_hat / c as bf16
      {
        const float* arow = out + ((size_t)(t - 1) * BB + b0) * SS;
        #pragma unroll
        for (int k = 0; k < 4; ++k) {
          int flat = k * 1024 + tid * 4;
          int row = flat >> 8, col = flat & 255;
          float4 v = *reinterpret_cast<const float4*>(arow + flat);
          float ci = rowA[row];
          unsigned p0 = (unsigned)f2bf(v.x * ci) | ((unsigned)f2bf(v.y * ci) << 16);
          unsigned p1 = (unsigned)f2bf(v.z * ci) | ((unsigned)f2bf(v.w * ci) << 16);
          *reinterpret_cast<uint2*>(&stage[row][col]) = make_uint2(p0, p1);
        }
      }
      __syncthreads();
      // gemm + on-the-fly a-mix combine
      float ys[2][4] = {{0.f,0.f,0.f,0.f},{0.f,0.f,0.f,0.f}};
      {
        bf16x8 af0 = *reinterpret_cast<const bf16x8*>(&stage[m_][(wave * 2 + 0) * 32 + q_ * 8]);
        bf16x8 af1 = *reinterpret_cast<const bf16x8*>(&stage[m_][(wave * 2 + 1) * 32 + q_ * 8]);
        float wreg[4][8];
        #pragma unroll
        for (int r = 0; r < 4; ++r) {
          *reinterpret_cast<float4*>(&wreg[r][0]) = *reinterpret_cast<const float4*>(&w8s[q_ * 4 + r][0]);
          *reinterpret_cast<float4*>(&wreg[r][4]) = *reinterpret_cast<const float4*>(&w8s[q_ * 4 + r][4]);
        }
        #pragma unroll
        for (int a = 0; a < 8; ++a) {
          #pragma unroll
          for (int nt = 0; nt < 2; ++nt) {
            f32x4 c = {0.f, 0.f, 0.f, 0.f};
            c = __builtin_amdgcn_mfma_f32_16x16x32_bf16(af0, bfrag[a][0][nt], c, 0, 0, 0);
            c = __builtin_amdgcn_mfma_f32_16x16x32_bf16(af1, bfrag[a][1][nt], c, 0, 0, 0);
            #pragma unroll
            for (int r = 0; r < 4; ++r) ys[nt][r] += wreg[r][a] * c[r];
          }
        }
      }
      #pragma unroll
      for (int nt = 0; nt < 2; ++nt)
        *reinterpret_cast<float4*>(&yred[wave][nt][lane][0]) =
            make_float4(ys[nt][0], ys[nt][1], ys[nt][2], ys[nt][3]);
      __syncthreads();
      // finalize: b_hat = exp(lx - M)*(y + S*EPS)
      {
        float csum = 0.f;
        float mm = rowM[frow];
        float* orow = out + ((size_t)t * BB + b0 + frow) * SS + jc0;
        #pragma unroll
        for (int nt = 0; nt < 2; ++nt) {
          float y = yred[0][nt][lsrc][rg_] + yred[1][nt][lsrc][rg_] +
                    yred[2][nt][lsrc][rg_] + yred[3][nt][lsrc][rg_];
          float bh = __expf(lxs[frow][nt * 16 + fcol] - mm) * (y + EPS_S);
          orow[nt * 16 + fcol] = bh;
          csum += bh;
        }
        #pragma unroll
        for (int o = 8; o >= 1; o >>= 1) csum += __shfl_down(csum, o, 16);
        if (fcol == 0) atomicAdd(&cvec[(size_t)t * BB + b0 + frow], csum);
      }
      __threadfence();
      __syncthreads();
      if (tid == 0) {
        atomicAdd(bar, 1);
        const int target = 8 * (t + 1);
        while (__hip_atomic_load(bar, __ATOMIC_ACQUIRE, __HIP_MEMORY_SCOPE_AGENT) < target)
          __builtin_amdgcn_s_sleep(1);
      }
      __syncthreads();
    }
  } else {
    // ---- bwd init: beta_hat[T-1] = 1
    {
      float rsum = 0.f;
      float* brow = beta + ((size_t)(TT - 1) * BB + b0 + frow) * SS + jc0;
      #pragma unroll
      for (int nt = 0; nt < 2; ++nt) { brow[nt * 16 + fcol] = 1.0f; rsum += 1.0f; }
      #pragma unroll
      for (int o = 8; o >= 1; o >>= 1) rsum += __shfl_down(rsum, o, 16);
      if (fcol == 0) atomicAdd(&rvec[(size_t)(TT - 1) * BB + b0 + frow], rsum);
    }
    __threadfence();
    __syncthreads();
    if (tid == 0) {
      atomicAdd(bar, 1);
      while (__hip_atomic_load(bar, __ATOMIC_ACQUIRE, __HIP_MEMORY_SCOPE_AGENT) < 8)
        __builtin_amdgcn_s_sleep(1);
    }
    __syncthreads();

    int step = 1;
    for (int t = TT - 2; t >= 0; --t, ++step) {
      if (tid < 16) {
        rowA[tid]  = 1.0f / rvec[(size_t)(t + 1) * BB + b0 + tid];
        rowM[tid]  = Mmax[(size_t)(t + 1) * BB + b0 + tid];
        rowMk[tid] = mask[(size_t)(t + 1) * BB + b0 + tid];
      }
      if (tid < 128) {
        int r = tid >> 3, a2 = tid & 7;
        w8s[r][a2] = a_in[((size_t)t * BB + b0 + r) * AA + a2];
      }
      __syncthreads();
      // stage g = exp(lx_{t+1}-M)*beta_hat_{t+1}/r ; rowG = sum_j g
      {
        const float* brow = beta + ((size_t)(t + 1) * BB + b0) * SS;
        const float* lrow = logp + ((size_t)(t + 1) * BB + b0) * SS;
        #pragma unroll
        for (int k = 0; k < 4; ++k) {
          int flat = k * 1024 + tid * 4;
          int row = flat >> 8, col = flat & 255;
          float4 bv = *reinterpret_cast<const float4*>(brow + flat);
          float4 lv = *reinterpret_cast<const float4*>(lrow + flat);
          float ri = rowA[row], mm = rowM[row];
          float g0 = __expf(lv.x - mm) * bv.x * ri;
          float g1 = __expf(lv.y - mm) * bv.y * ri;
          float g2 = __expf(lv.z - mm) * bv.z * ri;
          float g3 = __expf(lv.w - mm) * bv.w * ri;
          unsigned p0 = (unsigned)f2bf(g0) | ((unsigned)f2bf(g1) << 16);
          unsigned p1 = (unsigned)f2bf(g2) | ((unsigned)f2bf(g3) << 16);
          *reinterpret_cast<uint2*>(&stage[row][col]) = make_uint2(p0, p1);
          float part = (g0 + g1) + (g2 + g3);
          #pragma unroll
          for (int o = 32; o >= 1; o >>= 1) part += __shfl_down(part, o);
          if (lane == 0) rowG[row] = part;   // row = k*4 + wave, unique
        }
      }
      __syncthreads();
      float ys[2][4] = {{0.f,0.f,0.f,0.f},{0.f,0.f,0.f,0.f}};
      {
        bf16x8 af0 = *reinterpret_cast<const bf16x8*>(&stage[m_][(wave * 2 + 0) * 32 + q_ * 8]);
        bf16x8 af1 = *reinterpret_cast<const bf16x8*>(&stage[m_][(wave * 2 + 1) * 32 + q_ * 8]);
        float wreg[4][8];
        #pragma unroll
        for (int r = 0; r < 4; ++r) {
          *reinterpret_cast<float4*>(&wreg[r][0]) = *reinterpret_cast<const float4*>(&w8s[q_ * 4 + r][0]);
          *reinterpret_cast<float4*>(&wreg[r][4]) = *reinterpret_cast<const float4*>(&w8s[q_ * 4 + r][4]);
        }
        #pragma unroll
        for (int a = 0; a < 8; ++a) {
          #pragma unroll
          for (int nt = 0; nt < 2; ++nt) {
            f32x4 c = {0.f, 0.f, 0.f, 0.f};
            c = __builtin_amdgcn_mfma_f32_16x16x32_bf16(af0, bfrag[a][0][nt], c, 0, 0, 0);
            c = __builtin_amdgcn_mfma_f32_16x16x32_bf16(af1, bfrag[a][1][nt], c, 0, 0, 0);
            #pragma unroll
            for (int r = 0; r < 4; ++r) ys[nt][r] += wreg[r][a] * c[r];
          }
        }
      }
      #pragma unroll
      for (int nt = 0; nt < 2; ++nt)
        *reinterpret_cast<float4*>(&yred[wave][nt][lane][0]) =
            make_float4(ys[nt][0], ys[nt][1], ys[nt][2], ys[nt][3]);
      __syncthreads();
      {
        float rsum = 0.f;
        float eg = EPSF * rowG[frow];
        bool mk = (rowMk[frow] == 1.0f);
        float* browo = beta + ((size_t)t * BB + b0 + frow) * SS + jc0;
        #pragma unroll
        for (int nt = 0; nt < 2; ++nt) {
          float y = yred[0][nt][lsrc][rg_] + yred[1][nt][lsrc][rg_] +
                    yred[2][nt][lsrc][rg_] + yred[3][nt][lsrc][rg_];
          float val = mk ? (y + eg) : 1.0f;
          browo[nt * 16 + fcol] = val;
          rsum += val;
        }
        #pragma unroll
        for (int o = 8; o >= 1; o >>= 1) rsum += __shfl_down(rsum, o, 16);
        if (fcol == 0) atomicAdd(&rvec[(size_t)t * BB + b0 + frow], rsum);
      }
      __threadfence();
      __syncthreads();
      if (tid == 0) {
        atomicAdd(bar, 1);
        const int target = 8 * (step + 1);
        while (__hip_atomic_load(bar, __ATOMIC_ACQUIRE, __HIP_MEMORY_SCOPE_AGENT) < target)
          __builtin_amdgcn_s_sleep(1);
      }
      __syncthreads();
    }
  }
}

// ---------------- epilogue: q_z = softmax(log(b_hat + c*EPS) + log(beta_hat)) ----------------
__global__ __launch_bounds__(256) void k_qz(float* __restrict__ out,
    const float* __restrict__ beta, const float* __restrict__ cvec) {
  const float EPSF = 1e-6f;
  int tid = threadIdx.x;
  size_t row = (size_t)blockIdx.x * 8 + (tid >> 5);
  int l = tid & 31;
  float* po = out + row * SS + l * 8;
  const float* pb = beta + row * SS + l * 8;
  float ce = cvec[row] * EPSF;
  float4 v0 = *reinterpret_cast<const float4*>(po);
  float4 v1 = *reinterpret_cast<const float4*>(po + 4);
  float4 b0 = *reinterpret_cast<const float4*>(pb);
  float4 b1 = *reinterpret_cast<const float4*>(pb + 4);
  float z[8];
  z[0] = __logf(v0.x + ce) + __logf(b0.x);
  z[1] = __logf(v0.y + ce) + __logf(b0.y);
  z[2] = __logf(v0.z + ce) + __logf(b0.z);
  z[3] = __logf(v0.w + ce) + __logf(b0.w);
  z[4] = __logf(v1.x + ce) + __logf(b1.x);
  z[5] = __logf(v1.y + ce) + __logf(b1.y);
  z[6] = __logf(v1.z + ce) + __logf(b1.z);
  z[7] = __logf(v1.w + ce) + __logf(b1.w);
  float m = z[0];
  #pragma unroll
  for (int k = 1; k < 8; ++k) m = fmaxf(m, z[k]);
  #pragma unroll
  for (int o = 16; o >= 1; o >>= 1) m = fmaxf(m, __shfl_xor(m, o, 32));
  float e[8]; float s = 0.f;
  #pragma unroll
  for (int k = 0; k < 8; ++k) { e[k] = __expf(z[k] - m); s += e[k]; }
  #pragma unroll
  for (int o = 16; o >= 1; o >>= 1) s += __shfl_xor(s, o, 32);
  float inv = 1.0f / s;
  *reinterpret_cast<float4*>(po)     = make_float4(e[0]*inv, e[1]*inv, e[2]*inv, e[3]*inv);
  *reinterpret_cast<float4*>(po + 4) = make_float4(e[4]*inv, e[5]*inv, e[6]*inv, e[7]*inv);
}

extern "C" void kernel_launch(void* const* d_in, const int* in_sizes, int n_in,
                              void* d_out, int out_size, void* d_ws, size_t ws_size,
                              hipStream_t stream) {
  (void)in_sizes; (void)n_in; (void)out_size;
  const float* x   = (const float*)d_in[0];
  const float* a   = (const float*)d_in[1];
  const float* msk = (const float*)d_in[2];
  const float* mu  = (const float*)d_in[3];
  const float* lv  = (const float*)d_in[4];
  const float* wl  = (const float*)d_in[5];
  const float* s0  = (const float*)d_in[6];
  float* out = (float*)d_out;

  char* ws = (char*)d_ws;
  float* logp = (float*)ws;  ws += (size_t)TT * BB * SS * 4;
  float* beta = (float*)ws;  ws += (size_t)TT * BB * SS * 4;
  float* Mmax = (float*)ws;  ws += (size_t)TT * BB * 4;
  float* cvec = (float*)ws;  ws += (size_t)TT * BB * 4;
  float* rvec = (float*)ws;  ws += (size_t)TT * BB * 4;
  ushort_t* Wf = (ushort_t*)ws; ws += (size_t)AA * SS * SS * 2;
  ushort_t* Wb = (ushort_t*)ws; ws += (size_t)AA * SS * SS * 2;
  float* A1 = (float*)ws;    ws += (size_t)SS * DD * 4;
  float* A2 = (float*)ws;    ws += (size_t)SS * DD * 4;
  float* Cs = (float*)ws;    ws += 1024;
  float* lp0 = (float*)ws;   ws += 1024;
  int* bars = (int*)ws;      ws += 128;
  if (ws_size < (size_t)(ws - (char*)d_ws)) return;  // workspace too small -> clean fail

  hipMemsetAsync(cvec, 0, (size_t)2 * TT * BB * 4, stream);  // cvec + rvec (contiguous)
  hipMemsetAsync(bars, 0, 128, stream);

  k_params<<<SS, DD, 0, stream>>>(mu, lv, A1, A2, Cs);
  k_pi0<<<1, SS, 0, stream>>>(s0, lp0);
  k_trans<<<256, 256, 0, stream>>>(wl, Wf, Wb);
  k_logp<<<TT * BB / 32, 256, 0, stream>>>(x, A1, A2, Cs, logp, Mmax);
  k_recur<<<256, 256, 0, stream>>>(a, msk, out, beta, logp, Mmax, cvec, rvec, Wf, Wb, lp0, bars);
  k_qz<<<TT * BB / 8, 256, 0, stream>>>(out, beta, cvec);
}

// Round 2
// 4097.856 us; speedup vs baseline: 3.4252x; 3.4252x over previous
//
#include <hip/hip_runtime.h>
#include <hip/hip_bf16.h>

#define TT 512
#define BB 256
#define SS 256
#define AA 8
#define DD 64

typedef unsigned short ushort_t;
typedef __bf16 bf16x8 __attribute__((ext_vector_type(8)));
typedef float  f32x4  __attribute__((ext_vector_type(4)));

__device__ __forceinline__ ushort_t f2bf(float x) {
  union { float f; unsigned u; } v; v.f = x;
  unsigned r = (v.u + 0x7FFFu + ((v.u >> 16) & 1u)) >> 16;
  return (ushort_t)r;
}

__device__ __forceinline__ float ld_coherent(const float* p) {
  return __hip_atomic_load(p, __ATOMIC_RELAXED, __HIP_MEMORY_SCOPE_AGENT);
}
__device__ __forceinline__ void st_coherent(float* p, float v) {
  __hip_atomic_store(p, v, __ATOMIC_RELAXED, __HIP_MEMORY_SCOPE_AGENT);
}

// ---------------- prologue: per-state Gaussian params ----------------
__global__ __launch_bounds__(64) void k_params(const float* __restrict__ mu,
                                               const float* __restrict__ lv,
                                               float* __restrict__ A1, float* __restrict__ A2,
                                               float* __restrict__ Cs) {
  const float LOG2PI = 1.8378770664093453f;
  int s = blockIdx.x, d = threadIdx.x;
  float l = lv[s * DD + d], m_ = mu[s * DD + d];
  float inv = __expf(-l);
  A1[s * DD + d] = inv;
  A2[s * DD + d] = m_ * inv;
  float part = m_ * m_ * inv + l;
  #pragma unroll
  for (int o = 32; o >= 1; o >>= 1) part += __shfl_down(part, o);
  if (d == 0) Cs[s] = part + (float)DD * LOG2PI;
}

// ---------------- prologue: log_softmax of s0_logits ----------------
__global__ __launch_bounds__(256) void k_pi0(const float* __restrict__ s0, float* __restrict__ lp0) {
  __shared__ float red[4];
  int tid = threadIdx.x, ln = tid & 63, wv = tid >> 6;
  float v = s0[tid];
  float m = v;
  #pragma unroll
  for (int o = 32; o >= 1; o >>= 1) m = fmaxf(m, __shfl_xor(m, o));
  if (ln == 0) red[wv] = m;
  __syncthreads();
  m = fmaxf(fmaxf(red[0], red[1]), fmaxf(red[2], red[3]));
  __syncthreads();
  float e = __expf(v - m);
  float s = e;
  #pragma unroll
  for (int o = 32; o >= 1; o >>= 1) s += __shfl_xor(s, o);
  if (ln == 0) red[wv] = s;
  __syncthreads();
  s = red[0] + red[1] + red[2] + red[3];
  lp0[tid] = v - m - __logf(s);
}

// ---------------- prologue: softmax(w_logits) -> bf16 MFMA B-fragment layouts ----------------
__global__ __launch_bounds__(256) void k_trans(const float* __restrict__ wl,
                                               ushort_t* __restrict__ Wf, ushort_t* __restrict__ Wb) {
  int tid = threadIdx.x;
  int rl = tid >> 5, l = tid & 31;
  int row = blockIdx.x * 8 + rl;      // row = a*256 + i
  int a = row >> 8, i = row & 255;
  const float* src = wl + (size_t)row * 256 + l * 8;
  float v[8];
  *reinterpret_cast<float4*>(&v[0]) = *reinterpret_cast<const float4*>(src);
  *reinterpret_cast<float4*>(&v[4]) = *reinterpret_cast<const float4*>(src + 4);
  float m = v[0];
  #pragma unroll
  for (int k = 1; k < 8; ++k) m = fmaxf(m, v[k]);
  #pragma unroll
  for (int o = 16; o >= 1; o >>= 1) m = fmaxf(m, __shfl_xor(m, o, 32));
  float s = 0.f;
  #pragma unroll
  for (int k = 0; k < 8; ++k) { v[k] = __expf(v[k] - m); s += v[k]; }
  #pragma unroll
  for (int o = 16; o >= 1; o >>= 1) s += __shfl_xor(s, o, 32);
  float inv = 1.0f / s;
  #pragma unroll
  for (int k = 0; k < 8; ++k) {
    int j = l * 8 + k;
    ushort_t h = f2bf(v[k] * inv);
    size_t fi = (size_t)((a * 8 + (i >> 5)) * 16 + (j >> 4));
    Wf[fi * 512 + (((i >> 3) & 3) * 16 + (j & 15)) * 8 + (i & 7)] = h;
    size_t bi = (size_t)((a * 8 + (j >> 5)) * 16 + (i >> 4));
    Wb[bi * 512 + (((j >> 3) & 3) * 16 + (i & 15)) * 8 + (j & 7)] = h;
  }
}

// ---------------- logp_x [T,B,S] in fp32 + per-row max ----------------
__global__ __launch_bounds__(256) void k_logp(const float* __restrict__ x,
    const float* __restrict__ A1, const float* __restrict__ A2,
    const float* __restrict__ Cs, float* __restrict__ logp, float* __restrict__ Mmax) {
  __shared__ float sA1[64][64];
  __shared__ float sA2[64][64];
  int tid = threadIdx.x;
  int row = tid >> 3, dg = tid & 7;
  size_t row0 = (size_t)blockIdx.x * 32;
  const float* xp = x + (row0 + row) * DD + dg * 8;
  float xv[8];
  *reinterpret_cast<float4*>(&xv[0]) = *reinterpret_cast<const float4*>(xp);
  *reinterpret_cast<float4*>(&xv[4]) = *reinterpret_cast<const float4*>(xp + 4);
  float m = -3.0e38f;
  float* orow = logp + (row0 + row) * SS;
  for (int st = 0; st < 4; ++st) {
    __syncthreads();
    #pragma unroll
    for (int k = 0; k < 4; ++k) {
      int flat = k * 1024 + tid * 4;
      int sr = flat >> 6, sc = flat & 63;
      *reinterpret_cast<float4*>(&sA1[sr][sc]) = *reinterpret_cast<const float4*>(&A1[(size_t)(st * 64 + sr) * 64 + sc]);
      *reinterpret_cast<float4*>(&sA2[sr][sc]) = *reinterpret_cast<const float4*>(&A2[(size_t)(st * 64 + sr) * 64 + sc]);
    }
    __syncthreads();
    for (int s = 0; s < 64; ++s) {
      float acc = 0.f;
      #pragma unroll
      for (int j = 0; j < 8; ++j) {
        float t1 = __builtin_fmaf(sA1[s][dg * 8 + j], xv[j], -2.0f * sA2[s][dg * 8 + j]);
        acc = __builtin_fmaf(t1, xv[j], acc);
      }
      acc += __shfl_xor(acc, 1, 8);
      acc += __shfl_xor(acc, 2, 8);
      acc += __shfl_xor(acc, 4, 8);
      float lp = -0.5f * (acc + Cs[st * 64 + s]);
      m = fmaxf(m, lp);
      if (((s ^ dg) & 7) == 0) orow[st * 64 + s] = lp;
    }
  }
  if (dg == 0) Mmax[row0 + row] = m;
}

// ---------------- recursion ----------------
// No acquire/release fences anywhere: all cross-WG data moves with relaxed
// agent-scope (sc0 sc1) loads/stores that bypass L1/L2 and meet at the IF$;
// the flag barrier is waitcnt-drain + relaxed fetch_add + relaxed poll.
__global__ __launch_bounds__(256, 2) void k_recur(
    const float* __restrict__ a_in, const float* __restrict__ mask,
    float* __restrict__ out, float* __restrict__ beta,
    const float* __restrict__ logp, const float* __restrict__ Mmax,
    float* __restrict__ cvec, float* __restrict__ rvec,
    const ushort_t* __restrict__ Wf, const ushort_t* __restrict__ Wb,
    const float* __restrict__ lp0, int* __restrict__ bars) {
  const float EPSF  = 1e-6f;
  const float EPS_S = 256.0f * 1e-6f;
  const int tid  = threadIdx.x;
  const int lane = tid & 63;
  const int wave = tid >> 6;
  const int xcd  = blockIdx.x & 7;
  const int slot = blockIdx.x >> 3;
  const int wg   = slot & 7;                 // 8 WGs per group
  const int grpg = (slot >> 3) * 8 + xcd;    // 0..31 (group-mates share XCD heuristically)
  const bool isF = (grpg < 16);
  const int grp  = grpg & 15;
  const int b0   = grp * 16;
  const int jc0  = wg * 32;
  int* bar = bars + grpg;

  __shared__ float stage_f[16][260];         // raw fp32 staged A rows (pad 260: 2-way banks, free)
  __shared__ float w8s[16][8];
  __shared__ float yred[4][2][64][4];
  __shared__ float lxs[16][32];
  __shared__ float rowA[16];
  __shared__ float rowM[16];
  __shared__ float rowU[16];

  // persistent W fragments (bf16), per wave K-quarter, 2 n-tiles
  bf16x8 bfrag[8][2][2];
  {
    const ushort_t* Ws = isF ? Wf : Wb;
    #pragma unroll
    for (int a = 0; a < 8; ++a)
      #pragma unroll
      for (int kk = 0; kk < 2; ++kk)
        #pragma unroll
        for (int nt = 0; nt < 2; ++nt) {
          const int kc = wave * 2 + kk;
          const int fragid = (a * 8 + kc) * 16 + wg * 2 + nt;
          bfrag[a][kk][nt] = *reinterpret_cast<const bf16x8*>(Ws + (size_t)fragid * 512 + lane * 8);
        }
  }

  const int m_ = lane & 15;
  const int q_ = lane >> 4;
  const int frow = tid >> 4;
  const int fcol = tid & 15;
  const int lsrc = (frow >> 2) * 16 + fcol;
  const int rg_  = frow & 3;

  #define GROUP_BARRIER(target_) do {                                          \
    asm volatile("s_waitcnt vmcnt(0)" ::: "memory");                           \
    __syncthreads();                                                           \
    if (tid == 0) {                                                            \
      __hip_atomic_fetch_add(bar, 1, __ATOMIC_RELAXED, __HIP_MEMORY_SCOPE_AGENT); \
      while (__hip_atomic_load(bar, __ATOMIC_RELAXED, __HIP_MEMORY_SCOPE_AGENT) < (target_)) \
        __builtin_amdgcn_s_sleep(1);                                           \
    }                                                                          \
    __syncthreads();                                                           \
  } while (0)

  if (isF) {
    // ---- t = 0 init: alpha_hat(0) = exp(lx0 - M + logpi0)
    {
      float mm = Mmax[b0 + frow];
      float csum = 0.f;
      #pragma unroll
      for (int nt = 0; nt < 2; ++nt) {
        int j = jc0 + nt * 16 + fcol;
        float lx = logp[(size_t)(b0 + frow) * SS + j];
        float v = __expf(lx - mm + lp0[j]);
        st_coherent(&out[(size_t)(b0 + frow) * SS + j], v);
        csum += v;
      }
      #pragma unroll
      for (int o = 8; o >= 1; o >>= 1) csum += __shfl_down(csum, o, 16);
      if (fcol == 0) atomicAdd(&cvec[b0 + frow], csum);
    }
    GROUP_BARRIER(8);

    for (int t = 1; t < TT; ++t) {
      // phase ab: per-row scalars, a-mix, lx tile, raw alpha staging
      if (tid < 16) {
        rowA[tid] = 1.0f / ld_coherent(&cvec[(size_t)(t - 1) * BB + b0 + tid]);
        rowM[tid] = Mmax[(size_t)t * BB + b0 + tid];
      }
      if (tid < 128) {
        int r = tid >> 3, a2 = tid & 7;
        w8s[r][a2] = a_in[((size_t)(t - 1) * BB + b0 + r) * AA + a2];
      }
      {
        const float* lsp = logp + ((size_t)t * BB + b0 + frow) * SS + jc0;
        float2 v = *reinterpret_cast<const float2*>(lsp + fcol * 2);
        lxs[frow][fcol * 2] = v.x;
        lxs[frow][fcol * 2 + 1] = v.y;
      }
      {
        float* arow = out + ((size_t)(t - 1) * BB + b0) * SS;
        float av[16];
        #pragma unroll
        for (int j = 0; j < 16; ++j) av[j] = ld_coherent(arow + j * SS + tid);
        #pragma unroll
        for (int j = 0; j < 16; ++j) stage_f[j][tid] = av[j];
      }
      __syncthreads();
      // gemm + a-mix combine (normalize + cvt at fragment read)
      float ys[2][4] = {{0.f,0.f,0.f,0.f},{0.f,0.f,0.f,0.f}};
      {
        float ra = rowA[m_];
        const float* s0p = &stage_f[m_][(wave * 2 + 0) * 32 + q_ * 8];
        const float* s1p = &stage_f[m_][(wave * 2 + 1) * 32 + q_ * 8];
        float a0[8], a1[8];
        *reinterpret_cast<float4*>(&a0[0]) = *reinterpret_cast<const float4*>(s0p);
        *reinterpret_cast<float4*>(&a0[4]) = *reinterpret_cast<const float4*>(s0p + 4);
        *reinterpret_cast<float4*>(&a1[0]) = *reinterpret_cast<const float4*>(s1p);
        *reinterpret_cast<float4*>(&a1[4]) = *reinterpret_cast<const float4*>(s1p + 4);
        bf16x8 af0, af1;
        #pragma unroll
        for (int e = 0; e < 8; ++e) { af0[e] = (__bf16)(a0[e] * ra); af1[e] = (__bf16)(a1[e] * ra); }
        float wreg[4][8];
        #pragma unroll
        for (int r = 0; r < 4; ++r) {
          *reinterpret_cast<float4*>(&wreg[r][0]) = *reinterpret_cast<const float4*>(&w8s[q_ * 4 + r][0]);
          *reinterpret_cast<float4*>(&wreg[r][4]) = *reinterpret_cast<const float4*>(&w8s[q_ * 4 + r][4]);
        }
        #pragma unroll
        for (int a = 0; a < 8; ++a) {
          #pragma unroll
          for (int nt = 0; nt < 2; ++nt) {
            f32x4 c = {0.f, 0.f, 0.f, 0.f};
            c = __builtin_amdgcn_mfma_f32_16x16x32_bf16(af0, bfrag[a][0][nt], c, 0, 0, 0);
            c = __builtin_amdgcn_mfma_f32_16x16x32_bf16(af1, bfrag[a][1][nt], c, 0, 0, 0);
            #pragma unroll
            for (int r = 0; r < 4; ++r) ys[nt][r] += wreg[r][a] * c[r];
          }
        }
      }
      #pragma unroll
      for (int nt = 0; nt < 2; ++nt)
        *reinterpret_cast<float4*>(&yred[wave][nt][lane][0]) =
            make_float4(ys[nt][0], ys[nt][1], ys[nt][2], ys[nt][3]);
      __syncthreads();
      // finalize: alpha_hat = exp(lx - M)*(y + S*EPS)
      {
        float csum = 0.f;
        float mm = rowM[frow];
        float* orow = out + ((size_t)t * BB + b0 + frow) * SS + jc0;
        #pragma unroll
        for (int nt = 0; nt < 2; ++nt) {
          float y = yred[0][nt][lsrc][rg_] + yred[1][nt][lsrc][rg_] +
                    yred[2][nt][lsrc][rg_] + yred[3][nt][lsrc][rg_];
          float bh = __expf(lxs[frow][nt * 16 + fcol] - mm) * (y + EPS_S);
          st_coherent(orow + nt * 16 + fcol, bh);
          csum += bh;
        }
        #pragma unroll
        for (int o = 8; o >= 1; o >>= 1) csum += __shfl_down(csum, o, 16);
        if (fcol == 0) atomicAdd(&cvec[(size_t)t * BB + b0 + frow], csum);
      }
      GROUP_BARRIER(8 * (t + 1));
    }
  } else {
    // ---- bwd init: beta_hat[T-1] = 1
    {
      float rsum = 0.f;
      float* brow = beta + ((size_t)(TT - 1) * BB + b0 + frow) * SS + jc0;
      #pragma unroll
      for (int nt = 0; nt < 2; ++nt) { st_coherent(brow + nt * 16 + fcol, 1.0f); rsum += 1.0f; }
      #pragma unroll
      for (int o = 8; o >= 1; o >>= 1) rsum += __shfl_down(rsum, o, 16);
      if (fcol == 0) atomicAdd(&rvec[(size_t)(TT - 1) * BB + b0 + frow], rsum);
    }
    GROUP_BARRIER(8);

    int step = 1;
    for (int t = TT - 2; t >= 0; --t, ++step) {
      if (tid < 16)
        rowA[tid] = 1.0f / ld_coherent(&rvec[(size_t)(t + 1) * BB + b0 + tid]);
      if (tid < 128) {
        int r = tid >> 3, a2 = tid & 7;
        w8s[r][a2] = a_in[((size_t)t * BB + b0 + r) * AA + a2];
      }
      // stage u = exp(lx_{t+1}-M)*beta_hat_{t+1}  (1/r applied at fragment read)
      {
        float* brow = beta + ((size_t)(t + 1) * BB + b0) * SS;
        const float* lrow = logp + ((size_t)(t + 1) * BB + b0) * SS;
        const float* mrow = Mmax + (size_t)(t + 1) * BB + b0;
        float bv[16];
        #pragma unroll
        for (int j = 0; j < 16; ++j) bv[j] = ld_coherent(brow + j * SS + tid);
        #pragma unroll
        for (int j = 0; j < 16; ++j) {
          float lv = lrow[j * SS + tid];
          stage_f[j][tid] = __expf(lv - mrow[j]) * bv[j];
        }
      }
      __syncthreads();
      float ys[2][4] = {{0.f,0.f,0.f,0.f},{0.f,0.f,0.f,0.f}};
      {
        float ra = rowA[m_];
        const float* s0p = &stage_f[m_][(wave * 2 + 0) * 32 + q_ * 8];
        const float* s1p = &stage_f[m_][(wave * 2 + 1) * 32 + q_ * 8];
        float a0[8], a1[8];
        *reinterpret_cast<float4*>(&a0[0]) = *reinterpret_cast<const float4*>(s0p);
        *reinterpret_cast<float4*>(&a0[4]) = *reinterpret_cast<const float4*>(s0p + 4);
        *reinterpret_cast<float4*>(&a1[0]) = *reinterpret_cast<const float4*>(s1p);
        *reinterpret_cast<float4*>(&a1[4]) = *reinterpret_cast<const float4*>(s1p + 4);
        bf16x8 af0, af1;
        #pragma unroll
        for (int e = 0; e < 8; ++e) { af0[e] = (__bf16)(a0[e] * ra); af1[e] = (__bf16)(a1[e] * ra); }
        float wreg[4][8];
        #pragma unroll
        for (int r = 0; r < 4; ++r) {
          *reinterpret_cast<float4*>(&wreg[r][0]) = *reinterpret_cast<const float4*>(&w8s[q_ * 4 + r][0]);
          *reinterpret_cast<float4*>(&wreg[r][4]) = *reinterpret_cast<const float4*>(&w8s[q_ * 4 + r][4]);
        }
        #pragma unroll
        for (int a = 0; a < 8; ++a) {
          #pragma unroll
          for (int nt = 0; nt < 2; ++nt) {
            f32x4 c = {0.f, 0.f, 0.f, 0.f};
            c = __builtin_amdgcn_mfma_f32_16x16x32_bf16(af0, bfrag[a][0][nt], c, 0, 0, 0);
            c = __builtin_amdgcn_mfma_f32_16x16x32_bf16(af1, bfrag[a][1][nt], c, 0, 0, 0);
            #pragma unroll
            for (int r = 0; r < 4; ++r) ys[nt][r] += wreg[r][a] * c[r];
          }
        }
      }
      #pragma unroll
      for (int nt = 0; nt < 2; ++nt)
        *reinterpret_cast<float4*>(&yred[wave][nt][lane][0]) =
            make_float4(ys[nt][0], ys[nt][1], ys[nt][2], ys[nt][3]);
      // rowU[r] = sum_j stage_f[r][j] (4 rows per wave)
      {
        #pragma unroll
        for (int rr = 0; rr < 4; ++rr) {
          int r = wave * 4 + rr;
          float v = stage_f[r][lane] + stage_f[r][lane + 64] +
                    stage_f[r][lane + 128] + stage_f[r][lane + 192];
          #pragma unroll
          for (int o = 32; o >= 1; o >>= 1) v += __shfl_down(v, o);
          if (lane == 0) rowU[r] = v;
        }
      }
      __syncthreads();
      {
        float rsum = 0.f;
        float eg = EPSF * rowA[frow] * rowU[frow];
        bool mk = (mask[(size_t)(t + 1) * BB + b0 + frow] == 1.0f);
        float* browo = beta + ((size_t)t * BB + b0 + frow) * SS + jc0;
        #pragma unroll
        for (int nt = 0; nt < 2; ++nt) {
          float y = yred[0][nt][lsrc][rg_] + yred[1][nt][lsrc][rg_] +
                    yred[2][nt][lsrc][rg_] + yred[3][nt][lsrc][rg_];
          float val = mk ? (y + eg) : 1.0f;
          st_coherent(browo + nt * 16 + fcol, val);
          rsum += val;
        }
        #pragma unroll
        for (int o = 8; o >= 1; o >>= 1) rsum += __shfl_down(rsum, o, 16);
        if (fcol == 0) atomicAdd(&rvec[(size_t)t * BB + b0 + frow], rsum);
      }
      GROUP_BARRIER(8 * (step + 1));
    }
  }
  #undef GROUP_BARRIER
}

// ---------------- epilogue: q_z = softmax(log(alpha_hat + c*EPS) + log(beta_hat)) ----------------
__global__ __launch_bounds__(256) void k_qz(float* __restrict__ out,
    const float* __restrict__ beta, const float* __restrict__ cvec) {
  const float EPSF = 1e-6f;
  int tid = threadIdx.x;
  size_t row = (size_t)blockIdx.x * 8 + (tid >> 5);
  int l = tid & 31;
  float* po = out + row * SS + l * 8;
  const float* pb = beta + row * SS + l * 8;
  float ce = cvec[row] * EPSF;
  float4 v0 = *reinterpret_cast<const float4*>(po);
  float4 v1 = *reinterpret_cast<const float4*>(po + 4);
  float4 b0 = *reinterpret_cast<const float4*>(pb);
  float4 b1 = *reinterpret_cast<const float4*>(pb + 4);
  float z[8];
  z[0] = __logf(v0.x + ce) + __logf(b0.x);
  z[1] = __logf(v0.y + ce) + __logf(b0.y);
  z[2] = __logf(v0.z + ce) + __logf(b0.z);
  z[3] = __logf(v0.w + ce) + __logf(b0.w);
  z[4] = __logf(v1.x + ce) + __logf(b1.x);
  z[5] = __logf(v1.y + ce) + __logf(b1.y);
  z[6] = __logf(v1.z + ce) + __logf(b1.z);
  z[7] = __logf(v1.w + ce) + __logf(b1.w);
  float m = z[0];
  #pragma unroll
  for (int k = 1; k < 8; ++k) m = fmaxf(m, z[k]);
  #pragma unroll
  for (int o = 16; o >= 1; o >>= 1) m = fmaxf(m, __shfl_xor(m, o, 32));
  float e[8]; float s = 0.f;
  #pragma unroll
  for (int k = 0; k < 8; ++k) { e[k] = __expf(z[k] - m); s += e[k]; }
  #pragma unroll
  for (int o = 16; o >= 1; o >>= 1) s += __shfl_xor(s, o, 32);
  float inv = 1.0f / s;
  *reinterpret_cast<float4*>(po)     = make_float4(e[0]*inv, e[1]*inv, e[2]*inv, e[3]*inv);
  *reinterpret_cast<float4*>(po + 4) = make_float4(e[4]*inv, e[5]*inv, e[6]*inv, e[7]*inv);
}

extern "C" void kernel_launch(void* const* d_in, const int* in_sizes, int n_in,
                              void* d_out, int out_size, void* d_ws, size_t ws_size,
                              hipStream_t stream) {
  (void)in_sizes; (void)n_in; (void)out_size;
  const float* x   = (const float*)d_in[0];
  const float* a   = (const float*)d_in[1];
  const float* msk = (const float*)d_in[2];
  const float* mu  = (const float*)d_in[3];
  const float* lv  = (const float*)d_in[4];
  const float* wl  = (const float*)d_in[5];
  const float* s0  = (const float*)d_in[6];
  float* out = (float*)d_out;

  char* ws = (char*)d_ws;
  float* logp = (float*)ws;  ws += (size_t)TT * BB * SS * 4;
  float* beta = (float*)ws;  ws += (size_t)TT * BB * SS * 4;
  float* Mmax = (float*)ws;  ws += (size_t)TT * BB * 4;
  float* cvec = (float*)ws;  ws += (size_t)TT * BB * 4;
  float* rvec = (float*)ws;  ws += (size_t)TT * BB * 4;
  ushort_t* Wf = (ushort_t*)ws; ws += (size_t)AA * SS * SS * 2;
  ushort_t* Wb = (ushort_t*)ws; ws += (size_t)AA * SS * SS * 2;
  float* A1 = (float*)ws;    ws += (size_t)SS * DD * 4;
  float* A2 = (float*)ws;    ws += (size_t)SS * DD * 4;
  float* Cs = (float*)ws;    ws += 1024;
  float* lp0 = (float*)ws;   ws += 1024;
  int* bars = (int*)ws;      ws += 128;
  if (ws_size < (size_t)(ws - (char*)d_ws)) return;

  hipMemsetAsync(cvec, 0, (size_t)2 * TT * BB * 4, stream);  // cvec + rvec
  hipMemsetAsync(bars, 0, 128, stream);

  k_params<<<SS, DD, 0, stream>>>(mu, lv, A1, A2, Cs);
  k_pi0<<<1, SS, 0, stream>>>(s0, lp0);
  k_trans<<<256, 256, 0, stream>>>(wl, Wf, Wb);
  k_logp<<<TT * BB / 32, 256, 0, stream>>>(x, A1, A2, Cs, logp, Mmax);
  k_recur<<<256, 256, 0, stream>>>(a, msk, out, beta, logp, Mmax, cvec, rvec, Wf, Wb, lp0, bars);
  k_qz<<<TT * BB / 8, 256, 0, stream>>>(out, beta, cvec);
}

// Round 3
// 3145.748 us; speedup vs baseline: 4.4619x; 1.3027x over previous
//
#include <hip/hip_runtime.h>
#include <hip/hip_bf16.h>

#define TT 512
#define BB 256
#define SS 256
#define AA 8
#define DD 64

typedef unsigned short ushort_t;
typedef __bf16 bf16x8 __attribute__((ext_vector_type(8)));
typedef float  f32x4  __attribute__((ext_vector_type(4)));

__device__ __forceinline__ ushort_t f2bf(float x) {
  union { float f; unsigned u; } v; v.f = x;
  unsigned r = (v.u + 0x7FFFu + ((v.u >> 16) & 1u)) >> 16;
  return (ushort_t)r;
}

__device__ __forceinline__ float ld_coherent(const float* p) {
  return __hip_atomic_load(p, __ATOMIC_RELAXED, __HIP_MEMORY_SCOPE_AGENT);
}
__device__ __forceinline__ void st_coherent(float* p, float v) {
  __hip_atomic_store(p, v, __ATOMIC_RELAXED, __HIP_MEMORY_SCOPE_AGENT);
}
__device__ __forceinline__ int ld_flag(const int* p) {
  return __hip_atomic_load(p, __ATOMIC_RELAXED, __HIP_MEMORY_SCOPE_AGENT);
}
__device__ __forceinline__ void st_flag(int* p, int v) {
  __hip_atomic_store(p, v, __ATOMIC_RELAXED, __HIP_MEMORY_SCOPE_AGENT);
}

// ---------------- prologue: per-state Gaussian params ----------------
__global__ __launch_bounds__(64) void k_params(const float* __restrict__ mu,
                                               const float* __restrict__ lv,
                                               float* __restrict__ A1, float* __restrict__ A2,
                                               float* __restrict__ Cs) {
  const float LOG2PI = 1.8378770664093453f;
  int s = blockIdx.x, d = threadIdx.x;
  float l = lv[s * DD + d], m_ = mu[s * DD + d];
  float inv = __expf(-l);
  A1[s * DD + d] = inv;
  A2[s * DD + d] = m_ * inv;
  float part = m_ * m_ * inv + l;
  #pragma unroll
  for (int o = 32; o >= 1; o >>= 1) part += __shfl_down(part, o);
  if (d == 0) Cs[s] = part + (float)DD * LOG2PI;
}

// ---------------- prologue: log_softmax of s0_logits ----------------
__global__ __launch_bounds__(256) void k_pi0(const float* __restrict__ s0, float* __restrict__ lp0) {
  __shared__ float red[4];
  int tid = threadIdx.x, ln = tid & 63, wv = tid >> 6;
  float v = s0[tid];
  float m = v;
  #pragma unroll
  for (int o = 32; o >= 1; o >>= 1) m = fmaxf(m, __shfl_xor(m, o));
  if (ln == 0) red[wv] = m;
  __syncthreads();
  m = fmaxf(fmaxf(red[0], red[1]), fmaxf(red[2], red[3]));
  __syncthreads();
  float e = __expf(v - m);
  float s = e;
  #pragma unroll
  for (int o = 32; o >= 1; o >>= 1) s += __shfl_xor(s, o);
  if (ln == 0) red[wv] = s;
  __syncthreads();
  s = red[0] + red[1] + red[2] + red[3];
  lp0[tid] = v - m - __logf(s);
}

// ---------------- prologue: softmax(w_logits) -> bf16 MFMA B-fragment layouts ----------------
__global__ __launch_bounds__(256) void k_trans(const float* __restrict__ wl,
                                               ushort_t* __restrict__ Wf, ushort_t* __restrict__ Wb) {
  int tid = threadIdx.x;
  int rl = tid >> 5, l = tid & 31;
  int row = blockIdx.x * 8 + rl;      // row = a*256 + i
  int a = row >> 8, i = row & 255;
  const float* src = wl + (size_t)row * 256 + l * 8;
  float v[8];
  *reinterpret_cast<float4*>(&v[0]) = *reinterpret_cast<const float4*>(src);
  *reinterpret_cast<float4*>(&v[4]) = *reinterpret_cast<const float4*>(src + 4);
  float m = v[0];
  #pragma unroll
  for (int k = 1; k < 8; ++k) m = fmaxf(m, v[k]);
  #pragma unroll
  for (int o = 16; o >= 1; o >>= 1) m = fmaxf(m, __shfl_xor(m, o, 32));
  float s = 0.f;
  #pragma unroll
  for (int k = 0; k < 8; ++k) { v[k] = __expf(v[k] - m); s += v[k]; }
  #pragma unroll
  for (int o = 16; o >= 1; o >>= 1) s += __shfl_xor(s, o, 32);
  float inv = 1.0f / s;
  #pragma unroll
  for (int k = 0; k < 8; ++k) {
    int j = l * 8 + k;
    ushort_t h = f2bf(v[k] * inv);
    size_t fi = (size_t)((a * 8 + (i >> 5)) * 16 + (j >> 4));
    Wf[fi * 512 + (((i >> 3) & 3) * 16 + (j & 15)) * 8 + (i & 7)] = h;
    size_t bi = (size_t)((a * 8 + (j >> 5)) * 16 + (i >> 4));
    Wb[bi * 512 + (((j >> 3) & 3) * 16 + (i & 15)) * 8 + (j & 7)] = h;
  }
}

// ---------------- logp_x [T,B,S] in fp32 + per-row max ----------------
__global__ __launch_bounds__(256) void k_logp(const float* __restrict__ x,
    const float* __restrict__ A1, const float* __restrict__ A2,
    const float* __restrict__ Cs, float* __restrict__ logp, float* __restrict__ Mmax) {
  __shared__ float sA1[64][64];
  __shared__ float sA2[64][64];
  int tid = threadIdx.x;
  int row = tid >> 3, dg = tid & 7;
  size_t row0 = (size_t)blockIdx.x * 32;
  const float* xp = x + (row0 + row) * DD + dg * 8;
  float xv[8];
  *reinterpret_cast<float4*>(&xv[0]) = *reinterpret_cast<const float4*>(xp);
  *reinterpret_cast<float4*>(&xv[4]) = *reinterpret_cast<const float4*>(xp + 4);
  float m = -3.0e38f;
  float* orow = logp + (row0 + row) * SS;
  for (int st = 0; st < 4; ++st) {
    __syncthreads();
    #pragma unroll
    for (int k = 0; k < 4; ++k) {
      int flat = k * 1024 + tid * 4;
      int sr = flat >> 6, sc = flat & 63;
      *reinterpret_cast<float4*>(&sA1[sr][sc]) = *reinterpret_cast<const float4*>(&A1[(size_t)(st * 64 + sr) * 64 + sc]);
      *reinterpret_cast<float4*>(&sA2[sr][sc]) = *reinterpret_cast<const float4*>(&A2[(size_t)(st * 64 + sr) * 64 + sc]);
    }
    __syncthreads();
    for (int s = 0; s < 64; ++s) {
      float acc = 0.f;
      #pragma unroll
      for (int j = 0; j < 8; ++j) {
        float t1 = __builtin_fmaf(sA1[s][dg * 8 + j], xv[j], -2.0f * sA2[s][dg * 8 + j]);
        acc = __builtin_fmaf(t1, xv[j], acc);
      }
      acc += __shfl_xor(acc, 1, 8);
      acc += __shfl_xor(acc, 2, 8);
      acc += __shfl_xor(acc, 4, 8);
      float lp = -0.5f * (acc + Cs[st * 64 + s]);
      m = fmaxf(m, lp);
      if (((s ^ dg) & 7) == 0) orow[st * 64 + s] = lp;
    }
  }
  if (dg == 0) Mmax[row0 + row] = m;
}

// ---------------- recursion ----------------
// Store-based flag barrier (one padded line per WG), no atomic RMW anywhere.
// Cross-WG sums via per-WG partial stores (cpart/rpart) + consumer-side reduce.
__global__ __launch_bounds__(256, 2) void k_recur(
    const float* __restrict__ a_in, const float* __restrict__ mask,
    float* __restrict__ out, float* __restrict__ beta,
    const float* __restrict__ logp, const float* __restrict__ Mmax,
    float* __restrict__ cpart, float* __restrict__ rpart,
    const ushort_t* __restrict__ Wf, const ushort_t* __restrict__ Wb,
    const float* __restrict__ lp0, int* __restrict__ flags) {
  const float EPSF  = 1e-6f;
  const float EPS_S = 256.0f * 1e-6f;
  const int tid  = threadIdx.x;
  const int lane = tid & 63;
  const int wave = tid >> 6;
  const int xcd  = blockIdx.x & 7;
  const int slot = blockIdx.x >> 3;
  const int wg   = slot & 7;                 // 8 WGs per group
  const int grpg = (slot >> 3) * 8 + xcd;    // 0..31 (group-mates share XCD heuristically)
  const bool isF = (grpg < 16);
  const int grp  = grpg & 15;
  const int b0   = grp * 16;
  const int jc0  = wg * 32;
  int* myflag = flags + (grpg * 8 + wg) * 64;   // 256-B padded slot per WG

  __shared__ float stage_f[16][260];
  __shared__ float w8s[16][8];
  __shared__ float yred[4][2][64][4];
  __shared__ float rowA[16];
  __shared__ float rowU[16];

  // persistent W fragments (bf16), per wave K-quarter, 2 n-tiles
  bf16x8 bfrag[8][2][2];
  {
    const ushort_t* Ws = isF ? Wf : Wb;
    #pragma unroll
    for (int a = 0; a < 8; ++a)
      #pragma unroll
      for (int kk = 0; kk < 2; ++kk)
        #pragma unroll
        for (int nt = 0; nt < 2; ++nt) {
          const int kc = wave * 2 + kk;
          const int fragid = (a * 8 + kc) * 16 + wg * 2 + nt;
          bfrag[a][kk][nt] = *reinterpret_cast<const bf16x8*>(Ws + (size_t)fragid * 512 + lane * 8);
        }
  }

  const int m_ = lane & 15;
  const int q_ = lane >> 4;
  const int frow = tid >> 4;
  const int fcol = tid & 15;
  const int lsrc = (frow >> 2) * 16 + fcol;
  const int rg_  = frow & 3;

  #define GROUP_BARRIER(phase_) do {                                           \
    asm volatile("s_waitcnt vmcnt(0)" ::: "memory");                           \
    __syncthreads();                                                           \
    if (tid == 0) st_flag(myflag, (phase_));                                   \
    if (tid < 8) {                                                             \
      const int* fp = flags + (grpg * 8 + tid) * 64;                           \
      while (ld_flag(fp) < (phase_)) __builtin_amdgcn_s_sleep(1);              \
    }                                                                          \
    __syncthreads();                                                           \
  } while (0)

  if (isF) {
    // ---- t = 0 init: alpha_hat(0) = exp(lx0 - M + logpi0)
    {
      float mm = Mmax[b0 + frow];
      float csum = 0.f;
      #pragma unroll
      for (int nt = 0; nt < 2; ++nt) {
        int j = jc0 + nt * 16 + fcol;
        float lx = logp[(size_t)(b0 + frow) * SS + j];
        float v = __expf(lx - mm + lp0[j]);
        st_coherent(&out[(size_t)(b0 + frow) * SS + j], v);
        csum += v;
      }
      #pragma unroll
      for (int o = 8; o >= 1; o >>= 1) csum += __shfl_down(csum, o, 16);
      if (fcol == 0)
        st_coherent(&cpart[((size_t)grp * 16 + frow) * 8 + wg], csum);
    }
    // prefetch for t = 1
    float pf_ex0, pf_ex1, pf_w8v = 0.f;
    {
      float mmn = Mmax[(size_t)BB + b0 + frow];
      const float* lsp = logp + ((size_t)BB + b0 + frow) * SS + jc0;
      pf_ex0 = __expf(lsp[fcol] - mmn);
      pf_ex1 = __expf(lsp[16 + fcol] - mmn);
      if (tid < 128) pf_w8v = a_in[((size_t)0 * BB + b0 + (tid >> 3)) * AA + (tid & 7)];
    }
    GROUP_BARRIER(1);

    for (int t = 1; t < TT; ++t) {
      if (tid < 128) {
        w8s[tid >> 3][tid & 7] = pf_w8v;
        int r = tid >> 3, k = tid & 7;
        float v = ld_coherent(&cpart[(((size_t)(t - 1) * 16 + grp) * 16 + r) * 8 + k]);
        v += __shfl_down(v, 4, 8); v += __shfl_down(v, 2, 8); v += __shfl_down(v, 1, 8);
        if (k == 0) rowA[r] = 1.0f / v;
      }
      {
        float* arow = out + ((size_t)(t - 1) * BB + b0) * SS;
        float av[16];
        #pragma unroll
        for (int j = 0; j < 16; ++j) av[j] = ld_coherent(arow + j * SS + tid);
        #pragma unroll
        for (int j = 0; j < 16; ++j) stage_f[j][tid] = av[j];
      }
      __syncthreads();
      // gemm + a-mix combine (normalize + cvt at fragment read)
      float ys[2][4] = {{0.f,0.f,0.f,0.f},{0.f,0.f,0.f,0.f}};
      {
        float ra = rowA[m_];
        const float* s0p = &stage_f[m_][(wave * 2 + 0) * 32 + q_ * 8];
        const float* s1p = &stage_f[m_][(wave * 2 + 1) * 32 + q_ * 8];
        float a0[8], a1[8];
        *reinterpret_cast<float4*>(&a0[0]) = *reinterpret_cast<const float4*>(s0p);
        *reinterpret_cast<float4*>(&a0[4]) = *reinterpret_cast<const float4*>(s0p + 4);
        *reinterpret_cast<float4*>(&a1[0]) = *reinterpret_cast<const float4*>(s1p);
        *reinterpret_cast<float4*>(&a1[4]) = *reinterpret_cast<const float4*>(s1p + 4);
        bf16x8 af0, af1;
        #pragma unroll
        for (int e = 0; e < 8; ++e) { af0[e] = (__bf16)(a0[e] * ra); af1[e] = (__bf16)(a1[e] * ra); }
        float wreg[4][8];
        #pragma unroll
        for (int r = 0; r < 4; ++r) {
          *reinterpret_cast<float4*>(&wreg[r][0]) = *reinterpret_cast<const float4*>(&w8s[q_ * 4 + r][0]);
          *reinterpret_cast<float4*>(&wreg[r][4]) = *reinterpret_cast<const float4*>(&w8s[q_ * 4 + r][4]);
        }
        #pragma unroll
        for (int a = 0; a < 8; ++a) {
          #pragma unroll
          for (int nt = 0; nt < 2; ++nt) {
            f32x4 c = {0.f, 0.f, 0.f, 0.f};
            c = __builtin_amdgcn_mfma_f32_16x16x32_bf16(af0, bfrag[a][0][nt], c, 0, 0, 0);
            c = __builtin_amdgcn_mfma_f32_16x16x32_bf16(af1, bfrag[a][1][nt], c, 0, 0, 0);
            #pragma unroll
            for (int r = 0; r < 4; ++r) ys[nt][r] += wreg[r][a] * c[r];
          }
        }
      }
      #pragma unroll
      for (int nt = 0; nt < 2; ++nt)
        *reinterpret_cast<float4*>(&yred[wave][nt][lane][0]) =
            make_float4(ys[nt][0], ys[nt][1], ys[nt][2], ys[nt][3]);
      __syncthreads();
      // finalize: alpha_hat = pf_ex*(y + S*EPS)
      {
        float csum = 0.f;
        float* orow = out + ((size_t)t * BB + b0 + frow) * SS + jc0;
        float y0 = yred[0][0][lsrc][rg_] + yred[1][0][lsrc][rg_] +
                   yred[2][0][lsrc][rg_] + yred[3][0][lsrc][rg_];
        float bh0 = pf_ex0 * (y0 + EPS_S);
        st_coherent(orow + fcol, bh0); csum += bh0;
        float y1 = yred[0][1][lsrc][rg_] + yred[1][1][lsrc][rg_] +
                   yred[2][1][lsrc][rg_] + yred[3][1][lsrc][rg_];
        float bh1 = pf_ex1 * (y1 + EPS_S);
        st_coherent(orow + 16 + fcol, bh1); csum += bh1;
        #pragma unroll
        for (int o = 8; o >= 1; o >>= 1) csum += __shfl_down(csum, o, 16);
        if (fcol == 0)
          st_coherent(&cpart[(((size_t)t * 16 + grp) * 16 + frow) * 8 + wg], csum);
      }
      // prefetch for t+1
      if (t + 1 < TT) {
        float mmn = Mmax[(size_t)(t + 1) * BB + b0 + frow];
        const float* lsp = logp + ((size_t)(t + 1) * BB + b0 + frow) * SS + jc0;
        pf_ex0 = __expf(lsp[fcol] - mmn);
        pf_ex1 = __expf(lsp[16 + fcol] - mmn);
        if (tid < 128) pf_w8v = a_in[((size_t)t * BB + b0 + (tid >> 3)) * AA + (tid & 7)];
      }
      GROUP_BARRIER(t + 1);
    }
  } else {
    // ---- bwd init: beta_hat[T-1] = 1, rpart = 32 (per-WG partial of 256)
    {
      float* brow = beta + ((size_t)(TT - 1) * BB + b0 + frow) * SS + jc0;
      st_coherent(brow + fcol, 1.0f);
      st_coherent(brow + 16 + fcol, 1.0f);
      if (fcol == 0)
        st_coherent(&rpart[(((size_t)(TT - 1) * 16 + grp) * 16 + frow) * 8 + wg], 32.0f);
    }
    // prefetch for t = TT-2 (staging uses row t+1 = TT-1)
    float pf_e[16]; float pf_mk; float pf_w8v = 0.f;
    {
      const float* lrow = logp + ((size_t)(TT - 1) * BB + b0) * SS;
      const float* mrow = Mmax + (size_t)(TT - 1) * BB + b0;
      #pragma unroll
      for (int j = 0; j < 16; ++j) pf_e[j] = __expf(lrow[j * SS + tid] - mrow[j]);
      pf_mk = mask[(size_t)(TT - 1) * BB + b0 + frow];
      if (tid < 128) pf_w8v = a_in[((size_t)(TT - 2) * BB + b0 + (tid >> 3)) * AA + (tid & 7)];
    }
    GROUP_BARRIER(1);

    int step = 1;
    for (int t = TT - 2; t >= 0; --t, ++step) {
      if (tid < 128) {
        w8s[tid >> 3][tid & 7] = pf_w8v;
        int r = tid >> 3, k = tid & 7;
        float v = ld_coherent(&rpart[(((size_t)(t + 1) * 16 + grp) * 16 + r) * 8 + k]);
        v += __shfl_down(v, 4, 8); v += __shfl_down(v, 2, 8); v += __shfl_down(v, 1, 8);
        if (k == 0) rowA[r] = 1.0f / v;
      }
      {
        float* brow = beta + ((size_t)(t + 1) * BB + b0) * SS;
        float bv[16];
        #pragma unroll
        for (int j = 0; j < 16; ++j) bv[j] = ld_coherent(brow + j * SS + tid);
        #pragma unroll
        for (int j = 0; j < 16; ++j) stage_f[j][tid] = pf_e[j] * bv[j];
      }
      __syncthreads();
      float ys[2][4] = {{0.f,0.f,0.f,0.f},{0.f,0.f,0.f,0.f}};
      {
        float ra = rowA[m_];
        const float* s0p = &stage_f[m_][(wave * 2 + 0) * 32 + q_ * 8];
        const float* s1p = &stage_f[m_][(wave * 2 + 1) * 32 + q_ * 8];
        float a0[8], a1[8];
        *reinterpret_cast<float4*>(&a0[0]) = *reinterpret_cast<const float4*>(s0p);
        *reinterpret_cast<float4*>(&a0[4]) = *reinterpret_cast<const float4*>(s0p + 4);
        *reinterpret_cast<float4*>(&a1[0]) = *reinterpret_cast<const float4*>(s1p);
        *reinterpret_cast<float4*>(&a1[4]) = *reinterpret_cast<const float4*>(s1p + 4);
        bf16x8 af0, af1;
        #pragma unroll
        for (int e = 0; e < 8; ++e) { af0[e] = (__bf16)(a0[e] * ra); af1[e] = (__bf16)(a1[e] * ra); }
        float wreg[4][8];
        #pragma unroll
        for (int r = 0; r < 4; ++r) {
          *reinterpret_cast<float4*>(&wreg[r][0]) = *reinterpret_cast<const float4*>(&w8s[q_ * 4 + r][0]);
          *reinterpret_cast<float4*>(&wreg[r][4]) = *reinterpret_cast<const float4*>(&w8s[q_ * 4 + r][4]);
        }
        #pragma unroll
        for (int a = 0; a < 8; ++a) {
          #pragma unroll
          for (int nt = 0; nt < 2; ++nt) {
            f32x4 c = {0.f, 0.f, 0.f, 0.f};
            c = __builtin_amdgcn_mfma_f32_16x16x32_bf16(af0, bfrag[a][0][nt], c, 0, 0, 0);
            c = __builtin_amdgcn_mfma_f32_16x16x32_bf16(af1, bfrag[a][1][nt], c, 0, 0, 0);
            #pragma unroll
            for (int r = 0; r < 4; ++r) ys[nt][r] += wreg[r][a] * c[r];
          }
        }
      }
      #pragma unroll
      for (int nt = 0; nt < 2; ++nt)
        *reinterpret_cast<float4*>(&yred[wave][nt][lane][0]) =
            make_float4(ys[nt][0], ys[nt][1], ys[nt][2], ys[nt][3]);
      {
        #pragma unroll
        for (int rr = 0; rr < 4; ++rr) {
          int r = wave * 4 + rr;
          float v = stage_f[r][lane] + stage_f[r][lane + 64] +
                    stage_f[r][lane + 128] + stage_f[r][lane + 192];
          #pragma unroll
          for (int o = 32; o >= 1; o >>= 1) v += __shfl_down(v, o);
          if (lane == 0) rowU[r] = v;
        }
      }
      __syncthreads();
      {
        float rsum = 0.f;
        float eg = EPSF * rowA[frow] * rowU[frow];
        bool mk = (pf_mk == 1.0f);
        float* browo = beta + ((size_t)t * BB + b0 + frow) * SS + jc0;
        #pragma unroll
        for (int nt = 0; nt < 2; ++nt) {
          float y = yred[0][nt][lsrc][rg_] + yred[1][nt][lsrc][rg_] +
                    yred[2][nt][lsrc][rg_] + yred[3][nt][lsrc][rg_];
          float val = mk ? (y + eg) : 1.0f;
          st_coherent(browo + nt * 16 + fcol, val);
          rsum += val;
        }
        #pragma unroll
        for (int o = 8; o >= 1; o >>= 1) rsum += __shfl_down(rsum, o, 16);
        if (fcol == 0)
          st_coherent(&rpart[(((size_t)t * 16 + grp) * 16 + frow) * 8 + wg], rsum);
      }
      // prefetch for next iteration (processes t-1, staging row t)
      if (t > 0) {
        const float* lrow = logp + ((size_t)t * BB + b0) * SS;
        const float* mrow = Mmax + (size_t)t * BB + b0;
        #pragma unroll
        for (int j = 0; j < 16; ++j) pf_e[j] = __expf(lrow[j * SS + tid] - mrow[j]);
        pf_mk = mask[(size_t)t * BB + b0 + frow];
        if (tid < 128) pf_w8v = a_in[((size_t)(t - 1) * BB + b0 + (tid >> 3)) * AA + (tid & 7)];
      }
      GROUP_BARRIER(step + 1);
    }
  }
  #undef GROUP_BARRIER
}

// ---------------- epilogue: q_z = softmax(log(alpha_hat + c*EPS) + log(beta_hat)) ----------------
__global__ __launch_bounds__(256) void k_qz(float* __restrict__ out,
    const float* __restrict__ beta, const float* __restrict__ cpart) {
  const float EPSF = 1e-6f;
  int tid = threadIdx.x;
  size_t row = (size_t)blockIdx.x * 8 + (tid >> 5);
  int l = tid & 31;
  int tt = (int)(row >> 8);
  int b  = (int)(row & 255);
  int grp = b >> 4, r = b & 15;
  float pv = 0.f;
  if (l < 8) pv = cpart[(((size_t)tt * 16 + grp) * 16 + r) * 8 + l];
  pv += __shfl_down(pv, 4, 8); pv += __shfl_down(pv, 2, 8); pv += __shfl_down(pv, 1, 8);
  float ce = __shfl(pv, 0, 32) * EPSF;
  float* po = out + row * SS + l * 8;
  const float* pb = beta + row * SS + l * 8;
  float4 v0 = *reinterpret_cast<const float4*>(po);
  float4 v1 = *reinterpret_cast<const float4*>(po + 4);
  float4 b0 = *reinterpret_cast<const float4*>(pb);
  float4 b1 = *reinterpret_cast<const float4*>(pb + 4);
  float z[8];
  z[0] = __logf(v0.x + ce) + __logf(b0.x);
  z[1] = __logf(v0.y + ce) + __logf(b0.y);
  z[2] = __logf(v0.z + ce) + __logf(b0.z);
  z[3] = __logf(v0.w + ce) + __logf(b0.w);
  z[4] = __logf(v1.x + ce) + __logf(b1.x);
  z[5] = __logf(v1.y + ce) + __logf(b1.y);
  z[6] = __logf(v1.z + ce) + __logf(b1.z);
  z[7] = __logf(v1.w + ce) + __logf(b1.w);
  float m = z[0];
  #pragma unroll
  for (int k = 1; k < 8; ++k) m = fmaxf(m, z[k]);
  #pragma unroll
  for (int o = 16; o >= 1; o >>= 1) m = fmaxf(m, __shfl_xor(m, o, 32));
  float e[8]; float s = 0.f;
  #pragma unroll
  for (int k = 0; k < 8; ++k) { e[k] = __expf(z[k] - m); s += e[k]; }
  #pragma unroll
  for (int o = 16; o >= 1; o >>= 1) s += __shfl_xor(s, o, 32);
  float inv = 1.0f / s;
  *reinterpret_cast<float4*>(po)     = make_float4(e[0]*inv, e[1]*inv, e[2]*inv, e[3]*inv);
  *reinterpret_cast<float4*>(po + 4) = make_float4(e[4]*inv, e[5]*inv, e[6]*inv, e[7]*inv);
}

extern "C" void kernel_launch(void* const* d_in, const int* in_sizes, int n_in,
                              void* d_out, int out_size, void* d_ws, size_t ws_size,
                              hipStream_t stream) {
  (void)in_sizes; (void)n_in; (void)out_size;
  const float* x   = (const float*)d_in[0];
  const float* a   = (const float*)d_in[1];
  const float* msk = (const float*)d_in[2];
  const float* mu  = (const float*)d_in[3];
  const float* lv  = (const float*)d_in[4];
  const float* wl  = (const float*)d_in[5];
  const float* s0  = (const float*)d_in[6];
  float* out = (float*)d_out;

  char* ws = (char*)d_ws;
  float* logp  = (float*)ws;  ws += (size_t)TT * BB * SS * 4;
  float* beta  = (float*)ws;  ws += (size_t)TT * BB * SS * 4;
  float* Mmax  = (float*)ws;  ws += (size_t)TT * BB * 4;
  float* cpart = (float*)ws;  ws += (size_t)TT * BB * 8 * 4;   // [T][16][16][8]
  float* rpart = (float*)ws;  ws += (size_t)TT * BB * 8 * 4;
  ushort_t* Wf = (ushort_t*)ws; ws += (size_t)AA * SS * SS * 2;
  ushort_t* Wb = (ushort_t*)ws; ws += (size_t)AA * SS * SS * 2;
  float* A1 = (float*)ws;    ws += (size_t)SS * DD * 4;
  float* A2 = (float*)ws;    ws += (size_t)SS * DD * 4;
  float* Cs = (float*)ws;    ws += 1024;
  float* lp0 = (float*)ws;   ws += 1024;
  int* flags = (int*)ws;     ws += 256 * 64 * 4;               // 256 WG slots × 256 B
  if (ws_size < (size_t)(ws - (char*)d_ws)) return;

  hipMemsetAsync(flags, 0, 256 * 64 * 4, stream);

  k_params<<<SS, DD, 0, stream>>>(mu, lv, A1, A2, Cs);
  k_pi0<<<1, SS, 0, stream>>>(s0, lp0);
  k_trans<<<256, 256, 0, stream>>>(wl, Wf, Wb);
  k_logp<<<TT * BB / 32, 256, 0, stream>>>(x, A1, A2, Cs, logp, Mmax);
  k_recur<<<256, 256, 0, stream>>>(a, msk, out, beta, logp, Mmax, cpart, rpart, Wf, Wb, lp0, flags);
  k_qz<<<TT * BB / 8, 256, 0, stream>>>(out, beta, cpart);
}

// Round 4
// 2257.772 us; speedup vs baseline: 6.2167x; 1.3933x over previous
//
#include <hip/hip_runtime.h>
#include <hip/hip_bf16.h>

#define TT 512
#define BB 256
#define SS 256
#define AA 8
#define DD 64

typedef unsigned short ushort_t;
typedef unsigned long long u64_t;
typedef __bf16 bf16x8 __attribute__((ext_vector_type(8)));
typedef float  f32x4  __attribute__((ext_vector_type(4)));

__device__ __forceinline__ ushort_t f2bf(float x) {
  union { float f; unsigned u; } v; v.f = x;
  unsigned r = (v.u + 0x7FFFu + ((v.u >> 16) & 1u)) >> 16;
  return (ushort_t)r;
}
__device__ __forceinline__ float bf2f(unsigned h) {
  return __uint_as_float((h & 0xFFFFu) << 16);
}
__device__ __forceinline__ u64_t ld_u64(const u64_t* p) {
  return __hip_atomic_load(p, __ATOMIC_RELAXED, __HIP_MEMORY_SCOPE_AGENT);
}
__device__ __forceinline__ unsigned ld_u32(const unsigned* p) {
  return __hip_atomic_load(p, __ATOMIC_RELAXED, __HIP_MEMORY_SCOPE_AGENT);
}
__device__ __forceinline__ void st_u32(unsigned* p, unsigned v) {
  __hip_atomic_store(p, v, __ATOMIC_RELAXED, __HIP_MEMORY_SCOPE_AGENT);
}

// ---------------- prologue: per-state Gaussian params ----------------
__global__ __launch_bounds__(64) void k_params(const float* __restrict__ mu,
                                               const float* __restrict__ lv,
                                               float* __restrict__ A1, float* __restrict__ A2,
                                               float* __restrict__ Cs) {
  const float LOG2PI = 1.8378770664093453f;
  int s = blockIdx.x, d = threadIdx.x;
  float l = lv[s * DD + d], m_ = mu[s * DD + d];
  float inv = __expf(-l);
  A1[s * DD + d] = inv;
  A2[s * DD + d] = m_ * inv;
  float part = m_ * m_ * inv + l;
  #pragma unroll
  for (int o = 32; o >= 1; o >>= 1) part += __shfl_down(part, o);
  if (d == 0) Cs[s] = part + (float)DD * LOG2PI;
}

// ---------------- prologue: log_softmax of s0_logits ----------------
__global__ __launch_bounds__(256) void k_pi0(const float* __restrict__ s0, float* __restrict__ lp0) {
  __shared__ float red[4];
  int tid = threadIdx.x, ln = tid & 63, wv = tid >> 6;
  float v = s0[tid];
  float m = v;
  #pragma unroll
  for (int o = 32; o >= 1; o >>= 1) m = fmaxf(m, __shfl_xor(m, o));
  if (ln == 0) red[wv] = m;
  __syncthreads();
  m = fmaxf(fmaxf(red[0], red[1]), fmaxf(red[2], red[3]));
  __syncthreads();
  float e = __expf(v - m);
  float s = e;
  #pragma unroll
  for (int o = 32; o >= 1; o >>= 1) s += __shfl_xor(s, o);
  if (ln == 0) red[wv] = s;
  __syncthreads();
  s = red[0] + red[1] + red[2] + red[3];
  lp0[tid] = v - m - __logf(s);
}

// ---------------- prologue: softmax(w_logits) -> bf16 MFMA B-fragment layouts ----------------
__global__ __launch_bounds__(256) void k_trans(const float* __restrict__ wl,
                                               ushort_t* __restrict__ Wf, ushort_t* __restrict__ Wb) {
  int tid = threadIdx.x;
  int rl = tid >> 5, l = tid & 31;
  int row = blockIdx.x * 8 + rl;      // row = a*256 + i
  int a = row >> 8, i = row & 255;
  const float* src = wl + (size_t)row * 256 + l * 8;
  float v[8];
  *reinterpret_cast<float4*>(&v[0]) = *reinterpret_cast<const float4*>(src);
  *reinterpret_cast<float4*>(&v[4]) = *reinterpret_cast<const float4*>(src + 4);
  float m = v[0];
  #pragma unroll
  for (int k = 1; k < 8; ++k) m = fmaxf(m, v[k]);
  #pragma unroll
  for (int o = 16; o >= 1; o >>= 1) m = fmaxf(m, __shfl_xor(m, o, 32));
  float s = 0.f;
  #pragma unroll
  for (int k = 0; k < 8; ++k) { v[k] = __expf(v[k] - m); s += v[k]; }
  #pragma unroll
  for (int o = 16; o >= 1; o >>= 1) s += __shfl_xor(s, o, 32);
  float inv = 1.0f / s;
  #pragma unroll
  for (int k = 0; k < 8; ++k) {
    int j = l * 8 + k;
    ushort_t h = f2bf(v[k] * inv);
    size_t fi = (size_t)((a * 8 + (i >> 5)) * 16 + (j >> 4));
    Wf[fi * 512 + (((i >> 3) & 3) * 16 + (j & 15)) * 8 + (i & 7)] = h;
    size_t bi = (size_t)((a * 8 + (j >> 5)) * 16 + (i >> 4));
    Wb[bi * 512 + (((j >> 3) & 3) * 16 + (i & 15)) * 8 + (j & 7)] = h;
  }
}

// ---------------- logp_x [T,B,S] in fp32 + per-row max ----------------
__global__ __launch_bounds__(256) void k_logp(const float* __restrict__ x,
    const float* __restrict__ A1, const float* __restrict__ A2,
    const float* __restrict__ Cs, float* __restrict__ logp, float* __restrict__ Mmax) {
  __shared__ float sA1[64][64];
  __shared__ float sA2[64][64];
  int tid = threadIdx.x;
  int row = tid >> 3, dg = tid & 7;
  size_t row0 = (size_t)blockIdx.x * 32;
  const float* xp = x + (row0 + row) * DD + dg * 8;
  float xv[8];
  *reinterpret_cast<float4*>(&xv[0]) = *reinterpret_cast<const float4*>(xp);
  *reinterpret_cast<float4*>(&xv[4]) = *reinterpret_cast<const float4*>(xp + 4);
  float m = -3.0e38f;
  float* orow = logp + (row0 + row) * SS;
  for (int st = 0; st < 4; ++st) {
    __syncthreads();
    #pragma unroll
    for (int k = 0; k < 4; ++k) {
      int flat = k * 1024 + tid * 4;
      int sr = flat >> 6, sc = flat & 63;
      *reinterpret_cast<float4*>(&sA1[sr][sc]) = *reinterpret_cast<const float4*>(&A1[(size_t)(st * 64 + sr) * 64 + sc]);
      *reinterpret_cast<float4*>(&sA2[sr][sc]) = *reinterpret_cast<const float4*>(&A2[(size_t)(st * 64 + sr) * 64 + sc]);
    }
    __syncthreads();
    for (int s = 0; s < 64; ++s) {
      float acc = 0.f;
      #pragma unroll
      for (int j = 0; j < 8; ++j) {
        float t1 = __builtin_fmaf(sA1[s][dg * 8 + j], xv[j], -2.0f * sA2[s][dg * 8 + j]);
        acc = __builtin_fmaf(t1, xv[j], acc);
      }
      acc += __shfl_xor(acc, 1, 8);
      acc += __shfl_xor(acc, 2, 8);
      acc += __shfl_xor(acc, 4, 8);
      float lp = -0.5f * (acc + Cs[st * 64 + s]);
      m = fmaxf(m, lp);
      if (((s ^ dg) & 7) == 0) orow[st * 64 + s] = lp;
    }
  }
  if (dg == 0) Mmax[row0 + row] = m;
}

// ---------------- recursion: barrier-free tagged-mailbox pipeline ----------------
// amb/bmb: [2 parity][16 grp][16 row][256 col] u32 = (tag16 | bf16 payload)
// cmb/rmb: [2 parity][16 grp][16 row][8 wg]   u32 = (tag16 | bf16 row-partial-sum)
__global__ __launch_bounds__(256, 1) void k_recur(
    const float* __restrict__ a_in, const float* __restrict__ mask,
    float* __restrict__ out, float* __restrict__ beta,
    const float* __restrict__ logp, const float* __restrict__ Mmax,
    float* __restrict__ cpart,
    const ushort_t* __restrict__ Wf, const ushort_t* __restrict__ Wb,
    const float* __restrict__ lp0,
    unsigned* __restrict__ amb, unsigned* __restrict__ bmb,
    unsigned* __restrict__ cmb, unsigned* __restrict__ rmb) {
  const float EPSF  = 1e-6f;
  const float EPS_S = 256.0f * 1e-6f;
  const int tid  = threadIdx.x;
  const int lane = tid & 63;
  const int wave = tid >> 6;
  const int xcd  = blockIdx.x & 7;
  const int slot = blockIdx.x >> 3;
  const int wg   = slot & 7;                 // 8 WGs per group
  const int grpg = (slot >> 3) * 8 + xcd;    // 0..31
  const bool isF = (grpg < 16);
  const int grp  = grpg & 15;
  const int b0   = grp * 16;
  const int jc0  = wg * 32;

  __shared__ float yred[2][4][2][64][4];     // parity-double-buffered
  __shared__ float rowUp[2][4][16];

  // persistent W fragments (bf16), per wave K-quarter, 2 n-tiles
  bf16x8 bfrag[8][2][2];
  {
    const ushort_t* Ws = isF ? Wf : Wb;
    #pragma unroll
    for (int a = 0; a < 8; ++a)
      #pragma unroll
      for (int kk = 0; kk < 2; ++kk)
        #pragma unroll
        for (int nt = 0; nt < 2; ++nt) {
          const int kc = wave * 2 + kk;
          const int fragid = (a * 8 + kc) * 16 + wg * 2 + nt;
          bfrag[a][kk][nt] = *reinterpret_cast<const bf16x8*>(Ws + (size_t)fragid * 512 + lane * 8);
        }
  }

  const int m_ = lane & 15;
  const int q_ = lane >> 4;
  const int frow = tid >> 4;
  const int fcol = tid & 15;
  const int lsrc = (frow >> 2) * 16 + fcol;
  const int rg_  = frow & 3;
  const u64_t TAGMASK = 0xFFFF0000FFFF0000ULL;

  if (isF) {
    // ---- t = 0 init: alpha_hat(0) = exp(lx0 - M + logpi0)
    {
      float mm = Mmax[b0 + frow];
      float csum = 0.f;
      #pragma unroll
      for (int nt = 0; nt < 2; ++nt) {
        int j = jc0 + nt * 16 + fcol;
        float lx = logp[(size_t)(b0 + frow) * SS + j];
        float v = __expf(lx - mm + lp0[j]);
        out[(size_t)(b0 + frow) * SS + j] = v;
        st_u32(&amb[((size_t)(0 * 16 + grp) * 16 + frow) * 256 + j], (unsigned)f2bf(v));
        csum += v;
      }
      #pragma unroll
      for (int o = 8; o >= 1; o >>= 1) csum += __shfl_down(csum, o, 16);
      if (fcol == 0) {
        cpart[((size_t)grp * 16 + frow) * 8 + wg] = csum;
        st_u32(&cmb[((size_t)(0 * 16 + grp) * 16 + frow) * 8 + wg], (unsigned)f2bf(csum));
      }
    }

    for (int t = 1; t < TT; ++t) {
      const int par_r = (t - 1) & 1, par_w = t & 1;
      // ---- loop-top independent loads (overlap with poll)
      float wcur[4][8];
      {
        const float* ab = a_in + ((size_t)(t - 1) * BB + b0 + q_ * 4) * AA;
        #pragma unroll
        for (int r = 0; r < 4; ++r) {
          *reinterpret_cast<float4*>(&wcur[r][0]) = *reinterpret_cast<const float4*>(ab + r * AA);
          *reinterpret_cast<float4*>(&wcur[r][4]) = *reinterpret_cast<const float4*>(ab + r * AA + 4);
        }
      }
      float mmn = Mmax[(size_t)t * BB + b0 + frow];
      const float* lsp = logp + ((size_t)t * BB + b0 + frow) * SS + jc0;
      float ex0 = __expf(lsp[fcol] - mmn);
      float ex1 = __expf(lsp[16 + fcol] - mmn);

      // ---- poll fragment data + row-sum partials
      const u64_t* pr = (const u64_t*)(amb + (((size_t)par_r * 16 + grp) * 16 + m_) * 256);
      const u64_t* p0 = pr + wave * 32 + q_ * 4;
      const u64_t* p1 = p0 + 16;
      const unsigned* pc  = cmb + (((size_t)par_r * 16 + grp) * 16 + (lane >> 3)) * 8 + (lane & 7);
      const unsigned* pc2 = pc + 64;
      const unsigned tg = (unsigned)(t - 1);
      const u64_t pat = ((u64_t)tg << 48) | ((u64_t)tg << 16);
      u64_t d[8]; unsigned clo, chi;
      while (true) {
        #pragma unroll
        for (int k = 0; k < 4; ++k) { d[k] = ld_u64(p0 + k); d[4 + k] = ld_u64(p1 + k); }
        clo = ld_u32(pc); chi = ld_u32(pc2);
        bool ok = ((clo >> 16) == tg) & ((chi >> 16) == tg);
        #pragma unroll
        for (int k = 0; k < 8; ++k) ok &= ((d[k] & TAGMASK) == pat);
        if (__all(ok)) break;
      }
      // ra (1/row-sum) via octet reduce + broadcast
      float slo = bf2f(clo), shi = bf2f(chi);
      slo += __shfl_xor(slo, 4, 8); slo += __shfl_xor(slo, 2, 8); slo += __shfl_xor(slo, 1, 8);
      shi += __shfl_xor(shi, 4, 8); shi += __shfl_xor(shi, 2, 8); shi += __shfl_xor(shi, 1, 8);
      float vlo = __shfl(slo, (m_ & 7) * 8);
      float vhi = __shfl(shi, (m_ & 7) * 8);
      float ra = 1.0f / ((m_ < 8) ? vlo : vhi);

      // ---- fragments + GEMM + a-mix combine
      float ys[2][4] = {{0.f,0.f,0.f,0.f},{0.f,0.f,0.f,0.f}};
      {
        bf16x8 af0, af1;
        #pragma unroll
        for (int e = 0; e < 8; ++e) {
          unsigned h0 = (e & 1) ? (unsigned)(d[e >> 1] >> 32) : (unsigned)d[e >> 1];
          unsigned h1 = (e & 1) ? (unsigned)(d[4 + (e >> 1)] >> 32) : (unsigned)d[4 + (e >> 1)];
          af0[e] = (__bf16)(bf2f(h0) * ra);
          af1[e] = (__bf16)(bf2f(h1) * ra);
        }
        #pragma unroll
        for (int a = 0; a < 8; ++a) {
          #pragma unroll
          for (int nt = 0; nt < 2; ++nt) {
            f32x4 c = {0.f, 0.f, 0.f, 0.f};
            c = __builtin_amdgcn_mfma_f32_16x16x32_bf16(af0, bfrag[a][0][nt], c, 0, 0, 0);
            c = __builtin_amdgcn_mfma_f32_16x16x32_bf16(af1, bfrag[a][1][nt], c, 0, 0, 0);
            #pragma unroll
            for (int r = 0; r < 4; ++r) ys[nt][r] += wcur[r][a] * c[r];
          }
        }
      }
      #pragma unroll
      for (int nt = 0; nt < 2; ++nt)
        *reinterpret_cast<float4*>(&yred[par_w][wave][nt][lane][0]) =
            make_float4(ys[nt][0], ys[nt][1], ys[nt][2], ys[nt][3]);
      __syncthreads();
      // ---- finalize + publish (no drain, no flag)
      {
        float csum = 0.f;
        float* orow = out + ((size_t)t * BB + b0 + frow) * SS + jc0;
        unsigned* mrow = amb + (((size_t)par_w * 16 + grp) * 16 + frow) * 256 + jc0;
        float y0 = yred[par_w][0][0][lsrc][rg_] + yred[par_w][1][0][lsrc][rg_] +
                   yred[par_w][2][0][lsrc][rg_] + yred[par_w][3][0][lsrc][rg_];
        float bh0 = ex0 * (y0 + EPS_S);
        orow[fcol] = bh0;
        st_u32(mrow + fcol, ((unsigned)t << 16) | f2bf(bh0));
        csum += bh0;
        float y1 = yred[par_w][0][1][lsrc][rg_] + yred[par_w][1][1][lsrc][rg_] +
                   yred[par_w][2][1][lsrc][rg_] + yred[par_w][3][1][lsrc][rg_];
        float bh1 = ex1 * (y1 + EPS_S);
        orow[16 + fcol] = bh1;
        st_u32(mrow + 16 + fcol, ((unsigned)t << 16) | f2bf(bh1));
        csum += bh1;
        #pragma unroll
        for (int o = 8; o >= 1; o >>= 1) csum += __shfl_down(csum, o, 16);
        if (fcol == 0) {
          cpart[(((size_t)t * 16 + grp) * 16 + frow) * 8 + wg] = csum;
          st_u32(&cmb[(((size_t)par_w * 16 + grp) * 16 + frow) * 8 + wg],
                 ((unsigned)t << 16) | f2bf(csum));
        }
      }
    }
  } else {
    // ---- bwd init: beta_hat[T-1] = 1
    {
      const unsigned tg0 = (unsigned)(TT - 1);
      float* brow = beta + ((size_t)(TT - 1) * BB + b0 + frow) * SS + jc0;
      unsigned* mrow = bmb + (((size_t)((TT - 1) & 1) * 16 + grp) * 16 + frow) * 256 + jc0;
      brow[fcol] = 1.0f; brow[16 + fcol] = 1.0f;
      st_u32(mrow + fcol, (tg0 << 16) | 0x3F80u);
      st_u32(mrow + 16 + fcol, (tg0 << 16) | 0x3F80u);
      if (fcol == 0)
        st_u32(&rmb[(((size_t)((TT - 1) & 1) * 16 + grp) * 16 + frow) * 8 + wg],
               (tg0 << 16) | f2bf(32.0f));
    }

    for (int t = TT - 2; t >= 0; --t) {
      const int tr = t + 1;
      const int par_r = tr & 1, par_w = t & 1;
      // ---- loop-top independent loads
      float wcur[4][8];
      {
        const float* ab = a_in + ((size_t)t * BB + b0 + q_ * 4) * AA;
        #pragma unroll
        for (int r = 0; r < 4; ++r) {
          *reinterpret_cast<float4*>(&wcur[r][0]) = *reinterpret_cast<const float4*>(ab + r * AA);
          *reinterpret_cast<float4*>(&wcur[r][4]) = *reinterpret_cast<const float4*>(ab + r * AA + 4);
        }
      }
      float lp0v[8], lp1v[8];
      {
        const float* lrow = logp + ((size_t)tr * BB + b0 + m_) * SS + wave * 64 + q_ * 8;
        *reinterpret_cast<float4*>(&lp0v[0]) = *reinterpret_cast<const float4*>(lrow);
        *reinterpret_cast<float4*>(&lp0v[4]) = *reinterpret_cast<const float4*>(lrow + 4);
        *reinterpret_cast<float4*>(&lp1v[0]) = *reinterpret_cast<const float4*>(lrow + 32);
        *reinterpret_cast<float4*>(&lp1v[4]) = *reinterpret_cast<const float4*>(lrow + 36);
      }
      float mm_ = Mmax[(size_t)tr * BB + b0 + m_];
      float mk  = mask[(size_t)tr * BB + b0 + frow];

      // ---- poll
      const u64_t* pr = (const u64_t*)(bmb + (((size_t)par_r * 16 + grp) * 16 + m_) * 256);
      const u64_t* p0 = pr + wave * 32 + q_ * 4;
      const u64_t* p1 = p0 + 16;
      const unsigned* pc  = rmb + (((size_t)par_r * 16 + grp) * 16 + (lane >> 3)) * 8 + (lane & 7);
      const unsigned* pc2 = pc + 64;
      const unsigned tg = (unsigned)tr;
      const u64_t pat = ((u64_t)tg << 48) | ((u64_t)tg << 16);
      u64_t d[8]; unsigned clo, chi;
      while (true) {
        #pragma unroll
        for (int k = 0; k < 4; ++k) { d[k] = ld_u64(p0 + k); d[4 + k] = ld_u64(p1 + k); }
        clo = ld_u32(pc); chi = ld_u32(pc2);
        bool ok = ((clo >> 16) == tg) & ((chi >> 16) == tg);
        #pragma unroll
        for (int k = 0; k < 8; ++k) ok &= ((d[k] & TAGMASK) == pat);
        if (__all(ok)) break;
      }
      float slo = bf2f(clo), shi = bf2f(chi);
      slo += __shfl_xor(slo, 4, 8); slo += __shfl_xor(slo, 2, 8); slo += __shfl_xor(slo, 1, 8);
      shi += __shfl_xor(shi, 4, 8); shi += __shfl_xor(shi, 2, 8); shi += __shfl_xor(shi, 1, 8);
      float vlo = __shfl(slo, (m_ & 7) * 8);
      float vhi = __shfl(shi, (m_ & 7) * 8);
      float ri = 1.0f / ((m_ < 8) ? vlo : vhi);
      float vloF = __shfl(slo, (frow & 7) * 8);
      float vhiF = __shfl(shi, (frow & 7) * 8);
      float riF = 1.0f / ((frow < 8) ? vloF : vhiF);

      // ---- g = exp(lx-M)*beta_hat ; fragments + row partial
      float partial = 0.f;
      float ys[2][4] = {{0.f,0.f,0.f,0.f},{0.f,0.f,0.f,0.f}};
      {
        bf16x8 af0, af1;
        #pragma unroll
        for (int e = 0; e < 8; ++e) {
          unsigned h0 = (e & 1) ? (unsigned)(d[e >> 1] >> 32) : (unsigned)d[e >> 1];
          unsigned h1 = (e & 1) ? (unsigned)(d[4 + (e >> 1)] >> 32) : (unsigned)d[4 + (e >> 1)];
          float g0 = __expf(lp0v[e] - mm_) * bf2f(h0);
          float g1 = __expf(lp1v[e] - mm_) * bf2f(h1);
          partial += g0 + g1;
          af0[e] = (__bf16)(g0 * ri);
          af1[e] = (__bf16)(g1 * ri);
        }
        #pragma unroll
        for (int a = 0; a < 8; ++a) {
          #pragma unroll
          for (int nt = 0; nt < 2; ++nt) {
            f32x4 c = {0.f, 0.f, 0.f, 0.f};
            c = __builtin_amdgcn_mfma_f32_16x16x32_bf16(af0, bfrag[a][0][nt], c, 0, 0, 0);
            c = __builtin_amdgcn_mfma_f32_16x16x32_bf16(af1, bfrag[a][1][nt], c, 0, 0, 0);
            #pragma unroll
            for (int r = 0; r < 4; ++r) ys[nt][r] += wcur[r][a] * c[r];
          }
        }
      }
      partial += __shfl_xor(partial, 16);
      partial += __shfl_xor(partial, 32);
      if (q_ == 0) rowUp[par_w][wave][m_] = partial;
      #pragma unroll
      for (int nt = 0; nt < 2; ++nt)
        *reinterpret_cast<float4*>(&yred[par_w][wave][nt][lane][0]) =
            make_float4(ys[nt][0], ys[nt][1], ys[nt][2], ys[nt][3]);
      __syncthreads();
      // ---- finalize + publish
      {
        float rowU = rowUp[par_w][0][frow] + rowUp[par_w][1][frow] +
                     rowUp[par_w][2][frow] + rowUp[par_w][3][frow];
        float eg = EPSF * riF * rowU;
        bool mk1 = (mk == 1.0f);
        float rsum = 0.f;
        float* brow = beta + ((size_t)t * BB + b0 + frow) * SS + jc0;
        unsigned* mrow = bmb + (((size_t)par_w * 16 + grp) * 16 + frow) * 256 + jc0;
        #pragma unroll
        for (int nt = 0; nt < 2; ++nt) {
          float y = yred[par_w][0][nt][lsrc][rg_] + yred[par_w][1][nt][lsrc][rg_] +
                    yred[par_w][2][nt][lsrc][rg_] + yred[par_w][3][nt][lsrc][rg_];
          float val = mk1 ? (y + eg) : 1.0f;
          brow[nt * 16 + fcol] = val;
          st_u32(mrow + nt * 16 + fcol, ((unsigned)t << 16) | f2bf(val));
          rsum += val;
        }
        #pragma unroll
        for (int o = 8; o >= 1; o >>= 1) rsum += __shfl_down(rsum, o, 16);
        if (fcol == 0)
          st_u32(&rmb[(((size_t)par_w * 16 + grp) * 16 + frow) * 8 + wg],
                 ((unsigned)t << 16) | f2bf(rsum));
      }
    }
  }
}

// ---------------- epilogue: q_z = softmax(log(alpha_hat + c*EPS) + log(beta_hat)) ----------------
__global__ __launch_bounds__(256) void k_qz(float* __restrict__ out,
    const float* __restrict__ beta, const float* __restrict__ cpart) {
  const float EPSF = 1e-6f;
  int tid = threadIdx.x;
  size_t row = (size_t)blockIdx.x * 8 + (tid >> 5);
  int l = tid & 31;
  int tt = (int)(row >> 8);
  int b  = (int)(row & 255);
  int grp = b >> 4, r = b & 15;
  float pv = 0.f;
  if (l < 8) pv = cpart[(((size_t)tt * 16 + grp) * 16 + r) * 8 + l];
  pv += __shfl_down(pv, 4, 8); pv += __shfl_down(pv, 2, 8); pv += __shfl_down(pv, 1, 8);
  float ce = __shfl(pv, 0, 32) * EPSF;
  float* po = out + row * SS + l * 8;
  const float* pb = beta + row * SS + l * 8;
  float4 v0 = *reinterpret_cast<const float4*>(po);
  float4 v1 = *reinterpret_cast<const float4*>(po + 4);
  float4 b0 = *reinterpret_cast<const float4*>(pb);
  float4 b1 = *reinterpret_cast<const float4*>(pb + 4);
  float z[8];
  z[0] = __logf(v0.x + ce) + __logf(b0.x);
  z[1] = __logf(v0.y + ce) + __logf(b0.y);
  z[2] = __logf(v0.z + ce) + __logf(b0.z);
  z[3] = __logf(v0.w + ce) + __logf(b0.w);
  z[4] = __logf(v1.x + ce) + __logf(b1.x);
  z[5] = __logf(v1.y + ce) + __logf(b1.y);
  z[6] = __logf(v1.z + ce) + __logf(b1.z);
  z[7] = __logf(v1.w + ce) + __logf(b1.w);
  float m = z[0];
  #pragma unroll
  for (int k = 1; k < 8; ++k) m = fmaxf(m, z[k]);
  #pragma unroll
  for (int o = 16; o >= 1; o >>= 1) m = fmaxf(m, __shfl_xor(m, o, 32));
  float e[8]; float s = 0.f;
  #pragma unroll
  for (int k = 0; k < 8; ++k) { e[k] = __expf(z[k] - m); s += e[k]; }
  #pragma unroll
  for (int o = 16; o >= 1; o >>= 1) s += __shfl_xor(s, o, 32);
  float inv = 1.0f / s;
  *reinterpret_cast<float4*>(po)     = make_float4(e[0]*inv, e[1]*inv, e[2]*inv, e[3]*inv);
  *reinterpret_cast<float4*>(po + 4) = make_float4(e[4]*inv, e[5]*inv, e[6]*inv, e[7]*inv);
}

extern "C" void kernel_launch(void* const* d_in, const int* in_sizes, int n_in,
                              void* d_out, int out_size, void* d_ws, size_t ws_size,
                              hipStream_t stream) {
  (void)in_sizes; (void)n_in; (void)out_size;
  const float* x   = (const float*)d_in[0];
  const float* a   = (const float*)d_in[1];
  const float* msk = (const float*)d_in[2];
  const float* mu  = (const float*)d_in[3];
  const float* lv  = (const float*)d_in[4];
  const float* wl  = (const float*)d_in[5];
  const float* s0  = (const float*)d_in[6];
  float* out = (float*)d_out;

  char* ws = (char*)d_ws;
  float* logp  = (float*)ws;  ws += (size_t)TT * BB * SS * 4;
  float* beta  = (float*)ws;  ws += (size_t)TT * BB * SS * 4;
  float* Mmax  = (float*)ws;  ws += (size_t)TT * BB * 4;
  float* cpart = (float*)ws;  ws += (size_t)TT * BB * 8 * 4;   // [T][16][16][8]
  ushort_t* Wf = (ushort_t*)ws; ws += (size_t)AA * SS * SS * 2;
  ushort_t* Wb = (ushort_t*)ws; ws += (size_t)AA * SS * SS * 2;
  float* A1 = (float*)ws;    ws += (size_t)SS * DD * 4;
  float* A2 = (float*)ws;    ws += (size_t)SS * DD * 4;
  float* Cs = (float*)ws;    ws += 1024;
  float* lp0 = (float*)ws;   ws += 1024;
  unsigned* amb = (unsigned*)ws; ws += (size_t)2 * 16 * 16 * 256 * 4;  // 512 KB
  unsigned* bmb = (unsigned*)ws; ws += (size_t)2 * 16 * 16 * 256 * 4;  // 512 KB
  unsigned* cmb = (unsigned*)ws; ws += (size_t)2 * 16 * 16 * 8 * 4;    // 16 KB
  unsigned* rmb = (unsigned*)ws; ws += (size_t)2 * 16 * 16 * 8 * 4;    // 16 KB
  if (ws_size < (size_t)(ws - (char*)d_ws)) return;

  // invalidate all mailbox tags (0xFFFF != any step tag)
  hipMemsetAsync(amb, 0xFF, (size_t)(2 * 16 * 16 * 256 * 4) * 2 + (size_t)(2 * 16 * 16 * 8 * 4) * 2, stream);

  k_params<<<SS, DD, 0, stream>>>(mu, lv, A1, A2, Cs);
  k_pi0<<<1, SS, 0, stream>>>(s0, lp0);
  k_trans<<<256, 256, 0, stream>>>(wl, Wf, Wb);
  k_logp<<<TT * BB / 32, 256, 0, stream>>>(x, A1, A2, Cs, logp, Mmax);
  k_recur<<<256, 256, 0, stream>>>(a, msk, out, beta, logp, Mmax, cpart, Wf, Wb, lp0,
                                   amb, bmb, cmb, rmb);
  k_qz<<<TT * BB / 8, 256, 0, stream>>>(out, beta, cpart);
}